// Round 9
// baseline (1299.911 us; speedup 1.0000x reference)
//
#include <hip/hip_runtime.h>
#include <hip/hip_fp16.h>

// Problem constants (match reference)
#define B_      64
#define N_      256
#define M_      512
#define SIGMA_  1e-6f
#define RHO_    0.1f
#define ALPHA_  1.6f
#define BETA_   (-0.6f)   // 1 - ALPHA
#define ITERS_  200

#if defined(__has_builtin)
#if __has_builtin(__builtin_amdgcn_fdot2)
#define HAVE_FDOT2 1
#endif
#endif

typedef _Float16 h2_t __attribute__((ext_vector_type(2)));

__device__ __forceinline__ float fdot2f(__half2 a, __half2 b, float c) {
#ifdef HAVE_FDOT2
    return __builtin_amdgcn_fdot2(__builtin_bit_cast(h2_t, a),
                                  __builtin_bit_cast(h2_t, b), c, false);
#else
    return c + __low2float(a) * __low2float(b) + __high2float(a) * __high2float(b);
#endif
}

__device__ __forceinline__ float fdot2u(unsigned int a, unsigned int b, float c) {
    return fdot2f(__builtin_bit_cast(__half2, a), __builtin_bit_cast(__half2, b), c);
}

// bf16 round-to-nearest-even helpers
__device__ __forceinline__ unsigned short bf16rne(float f) {
    unsigned int u = __builtin_bit_cast(unsigned int, f);
    u += 0x7fffu + ((u >> 16) & 1u);
    return (unsigned short)(u >> 16);
}
__device__ __forceinline__ float bf16tof(unsigned short h) {
    unsigned int u = ((unsigned int)h) << 16;
    return __builtin_bit_cast(float, u);
}

__device__ __forceinline__ float f4c(const float4& v, int k) {
    return k == 0 ? v.x : k == 1 ? v.y : k == 2 ? v.z : v.w;
}

// ---------------------------------------------------------------------------
// Generic batched tiled GEMM (fp32 VALU) — fallback path only.
// ---------------------------------------------------------------------------
__global__ __launch_bounds__(256) void gemm_bt(
    const float* __restrict__ Af, const __half* __restrict__ Ah, int lda, long long sA, int tA,
    const float* __restrict__ Bf, int ldb, long long sB, int tB,
    const float* __restrict__ Dp, int ldd, long long sD,
    float* __restrict__ Cf, __half* __restrict__ Ch, int ldc, long long sC,
    float alpha, float beta, int Mx, int Nx, int Kx, int packPairs,
    float* __restrict__ Gdr, long long sGdr)
{
    __shared__ float as_[16][68];
    __shared__ float bs_[16][68];

    const int tid = threadIdx.x;
    const int b   = blockIdx.z;
    const int i0  = blockIdx.y * 64;
    const int j0  = blockIdx.x * 64;

    if (Af) Af += (size_t)b * sA;
    if (Ah) Ah += (size_t)b * sA;
    Bf += (size_t)b * sB;
    if (Dp) Dp += (size_t)b * sD;
    if (Cf) Cf += (size_t)b * sC;
    if (Ch) Ch += (size_t)b * sC;
    if (Gdr) Gdr += (size_t)b * sGdr;

    const int ty = tid >> 4;
    const int tx = tid & 15;

    float acc[4][4] = {};

    #pragma unroll 1
    for (int k0 = 0; k0 < Kx; k0 += 16) {
        if (tA) {
            const int kk = tid >> 4, i4 = (tid & 15) << 2;
            float4 v = *(const float4*)(Af + (size_t)(k0 + kk) * lda + i0 + i4);
            *(float4*)&as_[kk][i4] = v;
        } else {
            const int ii = tid >> 2, k4 = (tid & 3) << 2;
            if (Ah) {
                const __half2* hp = (const __half2*)(Ah + (size_t)(i0 + ii) * lda + k0 + k4);
                __half2 h0 = hp[0], h1 = hp[1];
                as_[k4 + 0][ii] = __low2float(h0);
                as_[k4 + 1][ii] = __high2float(h0);
                as_[k4 + 2][ii] = __low2float(h1);
                as_[k4 + 3][ii] = __high2float(h1);
            } else {
                float4 v = *(const float4*)(Af + (size_t)(i0 + ii) * lda + k0 + k4);
                as_[k4 + 0][ii] = v.x; as_[k4 + 1][ii] = v.y;
                as_[k4 + 2][ii] = v.z; as_[k4 + 3][ii] = v.w;
            }
        }
        if (tB) {
            const int jj = tid >> 2, k4 = (tid & 3) << 2;
            float4 v = *(const float4*)(Bf + (size_t)(j0 + jj) * ldb + k0 + k4);
            bs_[k4 + 0][jj] = v.x; bs_[k4 + 1][jj] = v.y;
            bs_[k4 + 2][jj] = v.z; bs_[k4 + 3][jj] = v.w;
        } else {
            const int kk = tid >> 4, j4 = (tid & 15) << 2;
            float4 v = *(const float4*)(Bf + (size_t)(k0 + kk) * ldb + j0 + j4);
            *(float4*)&bs_[kk][j4] = v;
        }
        __syncthreads();

        #pragma unroll
        for (int kk = 0; kk < 16; kk++) {
            float4 av = *(float4*)&as_[kk][ty << 2];
            float4 bv = *(float4*)&bs_[kk][tx << 2];
            acc[0][0] += av.x * bv.x; acc[0][1] += av.x * bv.y;
            acc[0][2] += av.x * bv.z; acc[0][3] += av.x * bv.w;
            acc[1][0] += av.y * bv.x; acc[1][1] += av.y * bv.y;
            acc[1][2] += av.y * bv.z; acc[1][3] += av.y * bv.w;
            acc[2][0] += av.z * bv.x; acc[2][1] += av.z * bv.y;
            acc[2][2] += av.z * bv.z; acc[2][3] += av.z * bv.w;
            acc[3][0] += av.w * bv.x; acc[3][1] += av.w * bv.y;
            acc[3][2] += av.w * bv.z; acc[3][3] += av.w * bv.w;
        }
        __syncthreads();
    }

    if (Ch) {
        if (packPairs) {
            __half2* C2 = (__half2*)Ch;
            const int mrow = i0 + (ty << 2);
            #pragma unroll
            for (int p = 0; p < 2; p++) {
                #pragma unroll
                for (int jj = 0; jj < 4; jj++) {
                    const float v0 = alpha * acc[2 * p][jj];
                    const float v1 = alpha * acc[2 * p + 1][jj];
                    __half2 h = __floats2half2_rn(v0, v1);
                    C2[(size_t)((mrow >> 1) + p) * ldc + j0 + (tx << 2) + jj] = h;
                    if (Gdr) {
                        const int col = j0 + (tx << 2) + jj;
                        const int r0  = mrow + 2 * p;
                        if (col == r0)          Gdr[col] = v0 - __low2float(h);
                        else if (col == r0 + 1) Gdr[col] = v1 - __high2float(h);
                    }
                }
            }
        } else {
            #pragma unroll
            for (int ii = 0; ii < 4; ii++) {
                #pragma unroll
                for (int jj = 0; jj < 4; jj++) {
                    Ch[(size_t)(i0 + (ty << 2) + ii) * ldc + j0 + (tx << 2) + jj] =
                        __float2half_rn(alpha * acc[ii][jj]);
                }
            }
        }
    } else {
        #pragma unroll
        for (int ii = 0; ii < 4; ii++) {
            const int m = i0 + (ty << 2) + ii;
            const int n = j0 + (tx << 2);
            float4 v;
            v.x = alpha * acc[ii][0]; v.y = alpha * acc[ii][1];
            v.z = alpha * acc[ii][2]; v.w = alpha * acc[ii][3];
            if (Dp) {
                float4 d = *(const float4*)(Dp + (size_t)m * ldd + n);
                v.x += beta * d.x; v.y += beta * d.y;
                v.z += beta * d.z; v.w += beta * d.w;
            }
            *(float4*)(Cf + (size_t)m * ldc + n) = v;
        }
    }
}

// ---------------------------------------------------------------------------
// MFMA split-bf16 GEMM with LDS-staged Y operand:  C = X · Y^T.
// ---------------------------------------------------------------------------
typedef __attribute__((ext_vector_type(8))) short bfrag;
typedef __attribute__((ext_vector_type(4))) float ffrag;

__global__ __launch_bounds__(256) void mfma_nt(
    const unsigned short* __restrict__ Xh, const unsigned short* __restrict__ Xl,
    const unsigned short* __restrict__ Yh, const unsigned short* __restrict__ Yl,
    int Kx, long long sX, long long sY,
    void* __restrict__ out0, void* __restrict__ out1,
    int ldc, long long sC, long long sC2, int mode,
    const float* __restrict__ Pd, float alpha)
{
    __shared__ unsigned short Ysh[2][64][264];

    const int tid = threadIdx.x;
    const int w   = tid >> 6;
    const int l   = tid & 63;
    const int b   = blockIdx.z;
    const int rowbase = blockIdx.y * 64 + w * 16;
    const int colbase = blockIdx.x * 64;
    const int lr = l & 15;
    const int q  = l >> 4;

    const unsigned short* xh = Xh + (size_t)b * sX + (size_t)(rowbase + lr) * Kx + q * 8;
    const unsigned short* xl = Xl + (size_t)b * sX + (size_t)(rowbase + lr) * Kx + q * 8;
    const unsigned short* ybh = Yh + (size_t)b * sY;
    const unsigned short* ybl = Yl + (size_t)b * sY;

    ffrag acc[4] = {};

    #pragma unroll 1
    for (int kc = 0; kc < Kx; kc += 256) {
        __syncthreads();
        #pragma unroll
        for (int e = 0; e < 8; e++) {
            const int idx = e * 256 + tid;
            const int c  = idx >> 5;
            const int kq = idx & 31;
            const size_t so = (size_t)(colbase + c) * Kx + kc + kq * 8;
            *(uint4*)&Ysh[0][c][kq * 8] = *(const uint4*)(ybh + so);
            *(uint4*)&Ysh[1][c][kq * 8] = *(const uint4*)(ybl + so);
        }
        __syncthreads();

        #pragma unroll 2
        for (int k0 = kc; k0 < kc + 256; k0 += 32) {
            bfrag ah = *(const bfrag*)(xh + k0);
            bfrag al = *(const bfrag*)(xl + k0);
            const int ko = (k0 - kc) + q * 8;
            #pragma unroll
            for (int t = 0; t < 4; t++) {
                bfrag bh = *(const bfrag*)&Ysh[0][16 * t + lr][ko];
                bfrag bl = *(const bfrag*)&Ysh[1][16 * t + lr][ko];
                acc[t] = __builtin_amdgcn_mfma_f32_16x16x32_bf16(ah, bh, acc[t], 0, 0, 0);
                acc[t] = __builtin_amdgcn_mfma_f32_16x16x32_bf16(ah, bl, acc[t], 0, 0, 0);
                acc[t] = __builtin_amdgcn_mfma_f32_16x16x32_bf16(al, bh, acc[t], 0, 0, 0);
            }
        }
    }

    if (mode == 0) {
        float* Cf = (float*)out0 + (size_t)b * sC;
        #pragma unroll
        for (int t = 0; t < 4; t++) {
            #pragma unroll
            for (int p = 0; p < 4; p++) {
                const int r  = rowbase + q * 4 + p;
                const int cc = colbase + 16 * t + lr;
                float v = alpha * acc[t][p];
                if (Pd && cc == r) v += Pd[b * 256 + r] + SIGMA_;
                Cf[(size_t)r * ldc + cc] = v;
            }
        }
    } else if (mode == 1) {
        unsigned short* Fh = (unsigned short*)out0 + (size_t)b * sC;
        unsigned short* Fl = (unsigned short*)out1 + (size_t)b * sC;
        #pragma unroll
        for (int t = 0; t < 4; t++) {
            #pragma unroll
            for (int p = 0; p < 4; p++) {
                const int r  = rowbase + q * 4 + p;
                const int cc = colbase + 16 * t + lr;
                const float v = acc[t][p];
                const unsigned short hh = bf16rne(v);
                Fh[(size_t)r * ldc + cc] = hh;
                Fl[(size_t)r * ldc + cc] = bf16rne(v - bf16tof(hh));
            }
        }
    } else {
        unsigned int* Gpp = (unsigned int*)out0 + (size_t)b * sC;
        float* Gd = (float*)out1 + (size_t)b * sC2;
        #pragma unroll
        for (int t = 0; t < 4; t++) {
            #pragma unroll
            for (int p2 = 0; p2 < 2; p2++) {
                const int r0 = rowbase + q * 4 + 2 * p2;
                const int cc = colbase + 16 * t + lr;
                const float v0 = acc[t][2 * p2], v1 = acc[t][2 * p2 + 1];
                __half2 h = __floats2half2_rn(v0, v1);
                Gpp[(size_t)(r0 >> 1) * ldc + cc] = __builtin_bit_cast(unsigned int, h);
                if (cc == r0)          Gd[cc] = v0 - __low2float(h);
                else if (cc == r0 + 1) Gd[cc] = v1 - __high2float(h);
            }
        }
    }
}

// ---------------------------------------------------------------------------
// prep_a: A -> AT split-bf16 and A split-bf16 in one pass
// ---------------------------------------------------------------------------
__global__ __launch_bounds__(256) void prep_a(
    const float* __restrict__ A, unsigned short* __restrict__ Th,
    unsigned short* __restrict__ Tl, unsigned short* __restrict__ Ahh,
    unsigned short* __restrict__ All)
{
    __shared__ float t_[64][65];
    const int b  = blockIdx.z;
    const int r0 = blockIdx.x * 64;
    const int c0 = blockIdx.y * 64;
    const int tid = threadIdx.x;
    const int ty = tid >> 4, tx = tid & 15;
    const float* Ab = A + (size_t)b * 131072;
    unsigned short* Ahb = Ahh + (size_t)b * 131072;
    unsigned short* Alb = All + (size_t)b * 131072;

    #pragma unroll
    for (int p = 0; p < 4; p++) {
        const int rr = ty + p * 16;
        const size_t o = (size_t)(r0 + rr) * 256 + c0 + tx * 4;
        float4 v = *(const float4*)(Ab + o);
        t_[rr][tx * 4 + 0] = v.x; t_[rr][tx * 4 + 1] = v.y;
        t_[rr][tx * 4 + 2] = v.z; t_[rr][tx * 4 + 3] = v.w;
        unsigned short h0 = bf16rne(v.x), h1 = bf16rne(v.y);
        unsigned short h2 = bf16rne(v.z), h3 = bf16rne(v.w);
        uint2 hp, lp;
        hp.x = (unsigned int)h0 | ((unsigned int)h1 << 16);
        hp.y = (unsigned int)h2 | ((unsigned int)h3 << 16);
        lp.x = (unsigned int)bf16rne(v.x - bf16tof(h0)) |
               ((unsigned int)bf16rne(v.y - bf16tof(h1)) << 16);
        lp.y = (unsigned int)bf16rne(v.z - bf16tof(h2)) |
               ((unsigned int)bf16rne(v.w - bf16tof(h3)) << 16);
        *(uint2*)(Ahb + o) = hp;
        *(uint2*)(Alb + o) = lp;
    }
    __syncthreads();

    unsigned short* Thb = Th + (size_t)b * 131072;
    unsigned short* Tlb = Tl + (size_t)b * 131072;
    #pragma unroll
    for (int p = 0; p < 4; p++) {
        const int ar = ty + p * 16;
        unsigned int hp[2], lp[2];
        #pragma unroll
        for (int d2 = 0; d2 < 2; d2++) {
            unsigned short h0, h1, l0, l1;
            {
                const float v = t_[tx * 4 + 2 * d2][ar];
                h0 = bf16rne(v); l0 = bf16rne(v - bf16tof(h0));
            }
            {
                const float v = t_[tx * 4 + 2 * d2 + 1][ar];
                h1 = bf16rne(v); l1 = bf16rne(v - bf16tof(h1));
            }
            hp[d2] = (unsigned int)h0 | ((unsigned int)h1 << 16);
            lp[d2] = (unsigned int)l0 | ((unsigned int)l1 << 16);
        }
        const size_t o = (size_t)(c0 + ar) * 512 + r0 + tx * 4;
        *(uint2*)(Thb + o) = make_uint2(hp[0], hp[1]);
        *(uint2*)(Tlb + o) = make_uint2(lp[0], lp[1]);
    }
}

// ---------------------------------------------------------------------------
// Mmat diag add (fallback path only)
// ---------------------------------------------------------------------------
__global__ void add_diag(float* __restrict__ Mm, const float* __restrict__ P)
{
    const int b = blockIdx.x, t = threadIdx.x;
    Mm[(size_t)b * 65536 + (size_t)t * 257] += P[b * 256 + t] + SIGMA_;
}

// ---------------------------------------------------------------------------
// XOR-quad swizzled 128x128 LDS matrix layout helpers
// ---------------------------------------------------------------------------
__device__ __forceinline__ int gja(int i, int j)
{
    return (i << 7) + ((((j >> 2) ^ (i & 31)) << 2) | (j & 3));
}
__device__ __forceinline__ float4 ldsq(const float* Mp, int row, int q)
{
    return *(const float4*)&Mp[(row << 7) + (((q ^ (row & 31)) << 2))];
}
__device__ __forceinline__ void stsq(float* Mp, int row, int q, float4 v)
{
    *(float4*)&Mp[(row << 7) + (((q ^ (row & 31)) << 2))] = v;
}

// ---------------------------------------------------------------------------
// Rank-16 blocked Gauss-Jordan on a 128x128 SPD matrix in LDS (R7-verified).
// ---------------------------------------------------------------------------
__device__ void gj_lds(float* Msh, float (&Dsh)[16][17], float (&CT)[16][136],
                       float (&RS)[16][136], float (&CDs)[16][136],
                       float (&rowB)[2][16], float (&colB)[2][16], float (&pB)[2],
                       int tid)
{
    const int di = tid >> 4;
    const int dj = tid & 15;

    #pragma unroll 1
    for (int t = 0; t < 8; t++) {
        const int tb = t << 4;

        float a = Msh[gja(tb + di, tb + dj)];
        #pragma unroll
        for (int g2 = 0; g2 < 2; g2++) {
            const int i0 = (dj << 2) + (g2 << 6);
            float4 cv;
            if ((i0 >> 4) == t) {
                cv.x = 0.f; cv.y = 0.f; cv.z = 0.f; cv.w = 0.f;
            } else {
                cv.x = Msh[gja(i0 + 0, tb + di)];
                cv.y = Msh[gja(i0 + 1, tb + di)];
                cv.z = Msh[gja(i0 + 2, tb + di)];
                cv.w = Msh[gja(i0 + 3, tb + di)];
            }
            *(float4*)&CT[di][i0] = cv;
        }
        __syncthreads();

        #pragma unroll 1
        for (int k = 0; k < 16; k++) {
            const int kb = k & 1;
            if (dj == k) colB[kb][di] = a;
            if (di == k) {
                rowB[kb][dj] = a;
                if (dj == k) pB[kb] = 1.0f / a;
            }
            __syncthreads();
            const float ip = pB[kb];
            const float rj = rowB[kb][dj];
            const float ci = colB[kb][di];
            if (di == k)      a = (dj == k) ? ip : rj * ip;
            else if (dj == k) a = -ci * ip;
            else              a -= ci * (rj * ip);
        }
        Dsh[di][dj] = a;
        __syncthreads();

        #pragma unroll
        for (int g2 = 0; g2 < 2; g2++) {
            const int j = (dj << 2) + (g2 << 6);
            float4 s; s.x = 0.f; s.y = 0.f; s.z = 0.f; s.w = 0.f;
            if ((j >> 4) != t) {
                #pragma unroll
                for (int m = 0; m < 16; m++) {
                    const float d = Dsh[di][m];
                    const float4 rv = ldsq(Msh, tb + m, j >> 2);
                    s.x += d * rv.x; s.y += d * rv.y;
                    s.z += d * rv.z; s.w += d * rv.w;
                }
            }
            *(float4*)&RS[di][j] = s;

            float4 sc; sc.x = 0.f; sc.y = 0.f; sc.z = 0.f; sc.w = 0.f;
            #pragma unroll
            for (int m = 0; m < 16; m++) {
                const float d = Dsh[m][di];
                const float4 cv = *(const float4*)&CT[m][j];
                sc.x += d * cv.x; sc.y += d * cv.y;
                sc.z += d * cv.z; sc.w += d * cv.w;
            }
            *(float4*)&CDs[di][j] = sc;
        }
        __syncthreads();

        {
            const int ty = di, tx = dj;
            float4 v0[8], v1[8];
            int cofs0[8], cofs1[8];
            #pragma unroll
            for (int r = 0; r < 8; r++) {
                const int i = (ty << 3) + r;
                const int e = i & 31;
                const int base = i << 7;
                cofs0[r] = base + ((((tx << 1)     ) ^ e) << 2);
                cofs1[r] = base + ((((tx << 1) | 1 ) ^ e) << 2);
                v0[r] = *(float4*)&Msh[cofs0[r]];
                v1[r] = *(float4*)&Msh[cofs1[r]];
            }
            #pragma unroll 1
            for (int k = 0; k < 16; k++) {
                const float4 r0 = *(const float4*)&RS[k][tx << 3];
                const float4 r1 = *(const float4*)&RS[k][(tx << 3) + 4];
                const float4 c0 = *(const float4*)&CT[k][ty << 3];
                const float4 c1 = *(const float4*)&CT[k][(ty << 3) + 4];
                const float cc[8] = {c0.x, c0.y, c0.z, c0.w,
                                     c1.x, c1.y, c1.z, c1.w};
                #pragma unroll
                for (int r = 0; r < 8; r++) {
                    const float c = cc[r];
                    v0[r].x -= c * r0.x; v0[r].y -= c * r0.y;
                    v0[r].z -= c * r0.z; v0[r].w -= c * r0.w;
                    v1[r].x -= c * r1.x; v1[r].y -= c * r1.y;
                    v1[r].z -= c * r1.z; v1[r].w -= c * r1.w;
                }
            }
            #pragma unroll
            for (int r = 0; r < 8; r++) {
                *(float4*)&Msh[cofs0[r]] = v0[r];
                *(float4*)&Msh[cofs1[r]] = v1[r];
            }
        }
        __syncthreads();

        #pragma unroll
        for (int g2 = 0; g2 < 2; g2++) {
            const int j = (dj << 2) + (g2 << 6);
            if ((j >> 4) != t) {
                stsq(Msh, tb + di, j >> 2, *(const float4*)&RS[di][j]);
                const float4 cd = *(const float4*)&CDs[di][j];
                Msh[gja(j + 0, tb + di)] = -cd.x;
                Msh[gja(j + 1, tb + di)] = -cd.y;
                Msh[gja(j + 2, tb + di)] = -cd.z;
                Msh[gja(j + 3, tb + di)] = -cd.w;
            }
        }
        Msh[gja(tb + di, tb + dj)] = Dsh[di][dj];
        __syncthreads();
    }
}

// ---------------------------------------------------------------------------
// gj128_blk — standalone kernel (fallback path)
// ---------------------------------------------------------------------------
__global__ __launch_bounds__(256) void gj128_blk(
    const float* __restrict__ src, int lsrc, long long ssrc,
    float* __restrict__ dst, int ldst, long long sdst)
{
    extern __shared__ float Msh[];
    __shared__ float Dsh[16][17];
    __shared__ float CT[16][136];
    __shared__ float RS[16][136];
    __shared__ float CDs[16][136];
    __shared__ float rowB[2][16], colB[2][16], pB[2];

    const int tid = threadIdx.x, b = blockIdx.x;
    src += (size_t)b * ssrc;
    dst += (size_t)b * sdst;

    for (int qd = 0; qd < 64; qd++) {
        const int idx = qd * 256 + tid;
        const int i = idx >> 7, j = idx & 127;
        Msh[gja(i, j)] = src[(size_t)i * lsrc + j];
    }
    __syncthreads();
    gj_lds(Msh, Dsh, CT, RS, CDs, rowB, colB, pB, tid);
    for (int qd = 0; qd < 64; qd++) {
        const int idx = qd * 256 + tid;
        const int i = idx >> 7, j = idx & 127;
        dst[(size_t)i * ldst + j] = Msh[gja(i, j)];
    }
}

// ---------------------------------------------------------------------------
// schur_inv: full Schur-complement inversion chain, one kernel (R8-verified).
// ---------------------------------------------------------------------------
__global__ __launch_bounds__(256) void schur_inv(
    const float* __restrict__ Mmat, float* __restrict__ Ebuf,
    float* __restrict__ Minv, unsigned short* __restrict__ Mh,
    unsigned short* __restrict__ Ml)
{
    __shared__ float A1[16384];
    __shared__ float A2[16384];
    __shared__ float Dsh[16][17];
    __shared__ float CT[16][136];
    __shared__ float RS[16][136];
    __shared__ float CDs[16][136];
    __shared__ float rowB[2][16], colB[2][16], pB[2];

    const int tid = threadIdx.x, b = blockIdx.x;
    const float* Mb = Mmat + (size_t)b * 65536;
    float* Eb = Ebuf + (size_t)b * 16384;
    float* Ib = Minv + (size_t)b * 65536;
    unsigned short* Mhb = Mh + (size_t)b * 65536;
    unsigned short* Mlb = Ml + (size_t)b * 65536;

    const int ty = tid >> 4, tx = tid & 15;

    for (int qd = 0; qd < 64; qd++) {
        const int idx = qd * 256 + tid;
        const int i = idx >> 7, j = idx & 127;
        A1[gja(i, j)] = Mb[(size_t)i * 256 + j];
    }
    __syncthreads();
    gj_lds(A1, Dsh, CT, RS, CDs, rowB, colB, pB, tid);

    for (int qd = 0; qd < 64; qd++) {
        const int idx = qd * 256 + tid;
        const int i = idx >> 7, j = idx & 127;
        Eb[(size_t)i * 128 + j] = A1[gja(i, j)];
        A2[gja(i, j)] = Mb[(size_t)(128 + i) * 256 + j];
    }
    __syncthreads();

    // T = M21 * E (in-place A2)
    {
        float acc[8][8] = {};
        #pragma unroll 1
        for (int k4 = 0; k4 < 32; k4++) {
            float4 mq[8];
            #pragma unroll
            for (int r = 0; r < 8; r++) mq[r] = ldsq(A2, 8 * ty + r, k4);
            #pragma unroll
            for (int kk = 0; kk < 4; kk++) {
                const int k = k4 * 4 + kk;
                const float4 e0 = ldsq(A1, k, 2 * tx);
                const float4 e1 = ldsq(A1, k, 2 * tx + 1);
                const float ev[8] = {e0.x, e0.y, e0.z, e0.w, e1.x, e1.y, e1.z, e1.w};
                #pragma unroll
                for (int r = 0; r < 8; r++) {
                    const float m = f4c(mq[r], kk);
                    #pragma unroll
                    for (int c = 0; c < 8; c++) acc[r][c] += m * ev[c];
                }
            }
        }
        __syncthreads();
        #pragma unroll
        for (int r = 0; r < 8; r++) {
            float4 o0, o1;
            o0.x = acc[r][0]; o0.y = acc[r][1]; o0.z = acc[r][2]; o0.w = acc[r][3];
            o1.x = acc[r][4]; o1.y = acc[r][5]; o1.z = acc[r][6]; o1.w = acc[r][7];
            stsq(A2, 8 * ty + r, 2 * tx, o0);
            stsq(A2, 8 * ty + r, 2 * tx + 1, o1);
        }
        __syncthreads();
    }

    // S = M22 - T * M12 -> A1
    {
        float acc[8][8];
        #pragma unroll
        for (int r = 0; r < 8; r++) {
            const float4 a0 = *(const float4*)&Mb[(size_t)(128 + 8 * ty + r) * 256 + 128 + 8 * tx];
            const float4 a1 = *(const float4*)&Mb[(size_t)(128 + 8 * ty + r) * 256 + 128 + 8 * tx + 4];
            acc[r][0] = a0.x; acc[r][1] = a0.y; acc[r][2] = a0.z; acc[r][3] = a0.w;
            acc[r][4] = a1.x; acc[r][5] = a1.y; acc[r][6] = a1.z; acc[r][7] = a1.w;
        }
        #pragma unroll 1
        for (int kt = 0; kt < 8; kt++) {
            __syncthreads();
            #pragma unroll
            for (int e = 0; e < 8; e++) {
                const int idx = e * 256 + tid;
                const int kk = idx >> 7, j = idx & 127;
                RS[kk][j] = Mb[(size_t)(kt * 16 + kk) * 256 + 128 + j];
            }
            __syncthreads();
            #pragma unroll 1
            for (int k2 = 0; k2 < 16; k2 += 4) {
                const int kq = (kt * 16 + k2) >> 2;
                float4 tq[8];
                #pragma unroll
                for (int r = 0; r < 8; r++) tq[r] = ldsq(A2, 8 * ty + r, kq);
                #pragma unroll
                for (int kk = 0; kk < 4; kk++) {
                    const float4 m0 = *(const float4*)&RS[k2 + kk][8 * tx];
                    const float4 m1 = *(const float4*)&RS[k2 + kk][8 * tx + 4];
                    const float mv[8] = {m0.x, m0.y, m0.z, m0.w, m1.x, m1.y, m1.z, m1.w};
                    #pragma unroll
                    for (int r = 0; r < 8; r++) {
                        const float t2 = f4c(tq[r], kk);
                        #pragma unroll
                        for (int c = 0; c < 8; c++) acc[r][c] -= t2 * mv[c];
                    }
                }
            }
        }
        __syncthreads();
        #pragma unroll
        for (int r = 0; r < 8; r++) {
            float4 o0, o1;
            o0.x = acc[r][0]; o0.y = acc[r][1]; o0.z = acc[r][2]; o0.w = acc[r][3];
            o1.x = acc[r][4]; o1.y = acc[r][5]; o1.z = acc[r][6]; o1.w = acc[r][7];
            stsq(A1, 8 * ty + r, 2 * tx, o0);
            stsq(A1, 8 * ty + r, 2 * tx + 1, o1);
        }
        __syncthreads();
    }

    gj_lds(A1, Dsh, CT, RS, CDs, rowB, colB, pB, tid);
    for (int qd = 0; qd < 64; qd++) {
        const int idx = qd * 256 + tid;
        const int i = idx >> 7, j = idx & 127;
        const float v = A1[gja(i, j)];
        const size_t o = (size_t)(128 + i) * 256 + 128 + j;
        Ib[o] = v;
        const unsigned short hh = bf16rne(v);
        Mhb[o] = hh; Mlb[o] = bf16rne(v - bf16tof(hh));
    }

    // V = Sinv * T (in-place A1)
    {
        float acc[8][8] = {};
        #pragma unroll 1
        for (int k4 = 0; k4 < 32; k4++) {
            float4 sq[8];
            #pragma unroll
            for (int r = 0; r < 8; r++) sq[r] = ldsq(A1, 8 * ty + r, k4);
            #pragma unroll
            for (int kk = 0; kk < 4; kk++) {
                const int k = k4 * 4 + kk;
                const float4 t0 = ldsq(A2, k, 2 * tx);
                const float4 t1 = ldsq(A2, k, 2 * tx + 1);
                const float tv[8] = {t0.x, t0.y, t0.z, t0.w, t1.x, t1.y, t1.z, t1.w};
                #pragma unroll
                for (int r = 0; r < 8; r++) {
                    const float m = f4c(sq[r], kk);
                    #pragma unroll
                    for (int c = 0; c < 8; c++) acc[r][c] += m * tv[c];
                }
            }
        }
        __syncthreads();
        #pragma unroll
        for (int r = 0; r < 8; r++) {
            float4 o0, o1;
            o0.x = acc[r][0]; o0.y = acc[r][1]; o0.z = acc[r][2]; o0.w = acc[r][3];
            o1.x = acc[r][4]; o1.y = acc[r][5]; o1.z = acc[r][6]; o1.w = acc[r][7];
            stsq(A1, 8 * ty + r, 2 * tx, o0);
            stsq(A1, 8 * ty + r, 2 * tx + 1, o1);
        }
        __syncthreads();
    }

    for (int qd = 0; qd < 64; qd++) {
        const int idx = qd * 256 + tid;
        const int i = idx >> 7, j = idx & 127;
        const float v = -A1[gja(i, j)];
        const size_t o = (size_t)(128 + i) * 256 + j;
        Ib[o] = v;
        const unsigned short hh = bf16rne(v);
        Mhb[o] = hh; Mlb[o] = bf16rne(v - bf16tof(hh));
    }
    for (int qd = 0; qd < 64; qd++) {
        const int idx = qd * 256 + tid;
        const int j = idx >> 7, i = idx & 127;
        const float v = -A1[gja(i, j)];
        const size_t o = (size_t)j * 256 + 128 + i;
        Ib[o] = v;
        const unsigned short hh = bf16rne(v);
        Mhb[o] = hh; Mlb[o] = bf16rne(v - bf16tof(hh));
    }

    // Minv11 = E + T^T * V
    {
        float acc[8][8] = {};
        #pragma unroll 1
        for (int k = 0; k < 128; k++) {
            const float4 t0 = ldsq(A2, k, 2 * ty);
            const float4 t1 = ldsq(A2, k, 2 * ty + 1);
            const float4 v0 = ldsq(A1, k, 2 * tx);
            const float4 v1 = ldsq(A1, k, 2 * tx + 1);
            const float tv[8] = {t0.x, t0.y, t0.z, t0.w, t1.x, t1.y, t1.z, t1.w};
            const float vv[8] = {v0.x, v0.y, v0.z, v0.w, v1.x, v1.y, v1.z, v1.w};
            #pragma unroll
            for (int r = 0; r < 8; r++)
                #pragma unroll
                for (int c = 0; c < 8; c++) acc[r][c] += tv[r] * vv[c];
        }
        #pragma unroll
        for (int r = 0; r < 8; r++) {
            const float4 e0 = *(const float4*)&Eb[(size_t)(8 * ty + r) * 128 + 8 * tx];
            const float4 e1 = *(const float4*)&Eb[(size_t)(8 * ty + r) * 128 + 8 * tx + 4];
            const float ev[8] = {e0.x, e0.y, e0.z, e0.w, e1.x, e1.y, e1.z, e1.w};
            #pragma unroll
            for (int c = 0; c < 8; c++) {
                const float v = acc[r][c] + ev[c];
                const size_t o = (size_t)(8 * ty + r) * 256 + 8 * tx + c;
                Ib[o] = v;
                const unsigned short hh = bf16rne(v);
                Mhb[o] = hh; Mlb[o] = bf16rne(v - bf16tof(hh));
            }
        }
    }
}

// ---------------------------------------------------------------------------
// Minv off-diagonal blocks (fallback path)
// ---------------------------------------------------------------------------
__global__ void assemble_offdiag(float* __restrict__ Minv, const float* __restrict__ V)
{
    const int b = blockIdx.x, tid = threadIdx.x;
    const float* Vb = V + (size_t)b * 16384;
    float* Mb = Minv + (size_t)b * 65536;
    for (int qd = 0; qd < 64; qd++) {
        const int idx = qd * 256 + tid;
        const int i = idx >> 7, j = idx & 127;
        const float v = -Vb[idx];
        Mb[(size_t)(128 + i) * 256 + j] = v;
        Mb[(size_t)j * 256 + 128 + i]   = v;
    }
}

// ---------------------------------------------------------------------------
// c0 = -Minv q ; d0 = A c0
// ---------------------------------------------------------------------------
__global__ __launch_bounds__(512) void c0d0_kernel(
    const float* __restrict__ Minv, const float* __restrict__ q,
    const float* __restrict__ A, float* __restrict__ c0, float* __restrict__ d0)
{
    __shared__ float qs[256], c0s[256];
    const int b = blockIdx.x, tid = threadIdx.x;
    const float* Mb = Minv + (size_t)b * 65536;

    if (tid < 256) qs[tid] = q[b * 256 + tid];
    __syncthreads();
    if (tid < 256) {
        float acc = 0.f;
        for (int j = 0; j < 256; j++)
            acc += Mb[(size_t)j * 256 + tid] * qs[j];
        c0s[tid] = -acc;
        c0[b * 256 + tid] = -acc;
    }
    __syncthreads();

    const int wid = tid >> 6, lane = tid & 63;
    const float* Ab = A + (size_t)b * 131072;
    for (int m = wid; m < 512; m += 8) {
        float4 a4 = *(const float4*)(Ab + (size_t)m * 256 + (lane << 2));
        float4 c4 = *(const float4*)&c0s[lane << 2];
        float acc = a4.x * c4.x + a4.y * c4.y + a4.z * c4.z + a4.w * c4.w;
        for (int off = 32; off > 0; off >>= 1) acc += __shfl_down(acc, off, 64);
        if (lane == 0) d0[b * 512 + m] = acc;
    }
}

// ---------------------------------------------------------------------------
// ADMM solver v5: ONE block per batch, 256 threads, 1 wave/SIMD (512-reg
// budget). Thread t owns columns (2t, 2t+1) COMPLETELY:
//   jj [0,48)   : LDS 96 KiB (verbatim layout, b64 conflict-free reads)
//   jj [48,256) : uint2 gc[208] register cache (416 regs/thread)
// Full column ownership -> no partial-sum reduction, no shuffle for r-pack,
// and with double-buffered rp_sh only ONE barrier per iteration.
// ---------------------------------------------------------------------------
__global__ __launch_bounds__(256, 1) void solver_2c(
    const unsigned int* __restrict__ Gp,
    const float* __restrict__ Gdr,
    const float* __restrict__ d0g,
    const float* __restrict__ lg, const float* __restrict__ ug,
    float* __restrict__ uout)
{
    __shared__ unsigned int Gsh[24576];      // jj 0..47 verbatim, 96 KiB
    __shared__ unsigned int rp_sh[2][256];   // double-buffered packed r

    const int tid = threadIdx.x;
    const int b   = blockIdx.x;

    const unsigned int* Gb = Gp + (size_t)b * 131072;

    // ---- stage jj[0,48) into LDS (verbatim, coalesced): 6144 uint4
    {
        const uint4* src4 = (const uint4*)Gb;
        uint4* dst4 = (uint4*)Gsh;
        #pragma unroll
        for (int n = 0; n < 24; n++)
            dst4[n * 256 + tid] = src4[n * 256 + tid];
    }

    // ---- register-cache jj [48,256) for columns (2t, 2t+1): 208 uint2
    const uint2* gb2 = (const uint2*)Gb + (size_t)48 * 256 + tid;
    uint2 gc[208];
    #pragma unroll
    for (int d = 0; d < 208; d++) gc[d] = gb2[(size_t)d * 256];

    // ---- per-column state (2 columns per thread), vectorized loads
    const float2 d0v  = *(const float2*)&d0g[b * 512 + 2 * tid];
    const float2 lv   = *(const float2*)&lg[b * 512 + 2 * tid];
    const float2 uv   = *(const float2*)&ug[b * 512 + 2 * tid];
    const float2 gdrv = *(const float2*)&Gdr[b * 512 + 2 * tid];
    float z0 = 0.f, z1 = 0.f, y0 = 0.f, y1 = 0.f, ua0 = 0.f, ua1 = 0.f;

    const unsigned int* lbase = Gsh + 2 * tid;

    __syncthreads();

    #pragma unroll 1
    for (int it = 0; it < ITERS_; it++) {
        // ---- r update + pack (rows 2t,2t+1 are owned here -> no shuffle)
        const float rv0 = RHO_ * z0 - y0;
        const float rv1 = RHO_ * z1 - y1;
        ua0 = BETA_ * ua0 + ALPHA_ * rv0;
        ua1 = BETA_ * ua1 + ALPHA_ * rv1;
        unsigned int* rp = rp_sh[it & 1];
        rp[tid] = __builtin_bit_cast(unsigned int, __floats2half2_rn(rv0, rv1));
        __syncthreads();   // single barrier: rp ready (prev-iter buffer safe)

        // ---- full-column GEMV: LDS jj[0,48) + registers jj[48,256)
        float a00 = 0.f, a01 = 0.f, a10 = 0.f, a11 = 0.f;
        #pragma unroll
        for (int j4 = 0; j4 < 12; j4++) {
            uint4 rr = *(const uint4*)&rp[j4 << 2];
            #pragma unroll
            for (int d = 0; d < 4; d++) {
                const int jj = (j4 << 2) + d;
                uint2 g = *(const uint2*)(lbase + (jj << 9));
                const unsigned int r =
                    d == 0 ? rr.x : d == 1 ? rr.y : d == 2 ? rr.z : rr.w;
                if (d & 1) { a01 = fdot2u(g.x, r, a01); a11 = fdot2u(g.y, r, a11); }
                else       { a00 = fdot2u(g.x, r, a00); a10 = fdot2u(g.y, r, a10); }
            }
        }
        #pragma unroll
        for (int k4 = 0; k4 < 52; k4++) {
            uint4 rr = *(const uint4*)&rp[48 / 4 * 4 + (k4 << 2)];
            #pragma unroll
            for (int d = 0; d < 4; d++) {
                const uint2 g = gc[(k4 << 2) + d];
                const unsigned int r =
                    d == 0 ? rr.x : d == 1 ? rr.y : d == 2 ? rr.z : rr.w;
                if (d & 1) { a01 = fdot2u(g.x, r, a01); a11 = fdot2u(g.y, r, a11); }
                else       { a00 = fdot2u(g.x, r, a00); a10 = fdot2u(g.y, r, a10); }
            }
        }

        // ---- relax / clip / dual (both columns, no reduction needed)
        {
            const float zt = d0v.x + (a00 + a01) + gdrv.x * rv0;
            const float zr = ALPHA_ * zt + (1.0f - ALPHA_) * z0;
            const float w  = zr + y0 * (1.0f / RHO_);
            const float zn = fminf(fmaxf(w, lv.x), uv.x);
            y0 = RHO_ * (w - zn);
            z0 = zn;
        }
        {
            const float zt = d0v.y + (a10 + a11) + gdrv.y * rv1;
            const float zr = ALPHA_ * zt + (1.0f - ALPHA_) * z1;
            const float w  = zr + y1 * (1.0f / RHO_);
            const float zn = fminf(fmaxf(w, lv.y), uv.y);
            y1 = RHO_ * (w - zn);
            z1 = zn;
        }
    }

    float2 uo; uo.x = ua0; uo.y = ua1;
    *(float2*)&uout[b * 512 + 2 * tid] = uo;
}

// ---------------------------------------------------------------------------
// x = c0 + Minv (A^T u)  — fp32 Minv (fallback)
// ---------------------------------------------------------------------------
__global__ __launch_bounds__(256) void finalx(
    const float* __restrict__ Minv, const float* __restrict__ c0,
    const float* __restrict__ uacc, const float* __restrict__ A,
    float* __restrict__ out)
{
    __shared__ float us2[512], t1s[256];
    const int b = blockIdx.x, tid = threadIdx.x;

    us2[tid]       = uacc[b * 512 + tid];
    us2[tid + 256] = uacc[b * 512 + 256 + tid];
    __syncthreads();

    const float* Ab = A + (size_t)b * 131072;
    float acc = 0.f;
    for (int m = 0; m < 512; m++)
        acc += Ab[(size_t)m * 256 + tid] * us2[m];
    t1s[tid] = acc;
    __syncthreads();

    const float* Mb = Minv + (size_t)b * 65536;
    float x = c0[b * 256 + tid];
    for (int j = 0; j < 256; j++)
        x += Mb[(size_t)j * 256 + tid] * t1s[j];
    out[b * 256 + tid] = x;
}

// ---------------------------------------------------------------------------
// x = c0 + (Mh+Ml) (A^T u)  — split-bf16 Minv (full path)
// ---------------------------------------------------------------------------
__global__ __launch_bounds__(256) void finalx_split(
    const unsigned short* __restrict__ Mh, const unsigned short* __restrict__ Ml,
    const float* __restrict__ c0, const float* __restrict__ uacc,
    const float* __restrict__ A, float* __restrict__ out)
{
    __shared__ float us2[512], t1s[256];
    const int b = blockIdx.x, tid = threadIdx.x;

    us2[tid]       = uacc[b * 512 + tid];
    us2[tid + 256] = uacc[b * 512 + 256 + tid];
    __syncthreads();

    const float* Ab = A + (size_t)b * 131072;
    float acc = 0.f;
    for (int m = 0; m < 512; m++)
        acc += Ab[(size_t)m * 256 + tid] * us2[m];
    t1s[tid] = acc;
    __syncthreads();

    const unsigned short* Mhb = Mh + (size_t)b * 65536;
    const unsigned short* Mlb = Ml + (size_t)b * 65536;
    float x = c0[b * 256 + tid];
    for (int j = 0; j < 256; j++) {
        const float m = bf16tof(Mhb[(size_t)j * 256 + tid]) +
                        bf16tof(Mlb[(size_t)j * 256 + tid]);
        x += m * t1s[j];
    }
    out[b * 256 + tid] = x;
}

// ---------------------------------------------------------------------------
// Host launcher
// ---------------------------------------------------------------------------
extern "C" void kernel_launch(void* const* d_in, const int* in_sizes, int n_in,
                              void* d_out, int out_size, void* d_ws, size_t ws_size,
                              hipStream_t stream)
{
    (void)in_sizes; (void)n_in; (void)out_size;

    const float* P = (const float*)d_in[0];
    const float* q = (const float*)d_in[1];
    const float* A = (const float*)d_in[2];
    const float* l = (const float*)d_in[3];
    const float* u = (const float*)d_in[4];
    float* out = (float*)d_out;
    char* ws = (char*)d_ws;

    (void)hipFuncSetAttribute(reinterpret_cast<const void*>(&gj128_blk),
                              hipFuncAttributeMaxDynamicSharedMemorySize, 65536);

    const bool fullPath = (ws_size >= (161ull << 20));

    if (fullPath) {
        float*  Mmat = (float*)(ws);
        float*  Minv = (float*)(ws + (16ull << 20));
        float*  Ebuf = (float*)(ws + (32ull << 20));
        unsigned short* Mh  = (unsigned short*)(ws + (48ull << 20));
        unsigned short* Ml  = (unsigned short*)(ws + (56ull << 20));
        unsigned short* Ahh = (unsigned short*)(ws + (64ull << 20));
        unsigned short* All = (unsigned short*)(ws + (80ull << 20));
        unsigned short* Fhh = (unsigned short*)(ws + (96ull << 20));   // = AT_h early
        unsigned short* Fll = (unsigned short*)(ws + (112ull << 20));  // = AT_l early
        unsigned int*   G   = (unsigned int*)(ws + (128ull << 20));
        char* tail = ws + (160ull << 20);
        float* c0  = (float*)(tail);
        float* d0  = (float*)(tail + 65536);
        float* ua  = (float*)(tail + 196608);
        float* Gdr = (float*)(tail + 327680);

        // 1) A^T split-bf16 (F slots) + A split-bf16, one pass
        prep_a<<<dim3(8, 4, 64), 256, 0, stream>>>(A, Fhh, Fll, Ahh, All);

        // 2) Mmat = RHO*(A^T)(A^T)^T + diag(P)+sigma   [MFMA, LDS-staged Y]
        mfma_nt<<<dim3(4, 4, 64), 256, 0, stream>>>(
            Fhh, Fll, Fhh, Fll, 512, 131072, 131072,
            (void*)Mmat, nullptr, 256, 65536, 0, 0, P, RHO_);

        // 3) Full Schur inversion chain (+ split-bf16 Minv), one kernel
        schur_inv<<<64, 256, 0, stream>>>(Mmat, Ebuf, Minv, Mh, Ml);

        // 4) c0 = -Minv q ; d0 = A c0
        c0d0_kernel<<<64, 512, 0, stream>>>(Minv, q, A, c0, d0);

        // 5) F = A * Minv^T -> split-bf16 (overwrites AT slots)
        mfma_nt<<<dim3(4, 8, 64), 256, 0, stream>>>(
            Ahh, All, Mh, Ml, 256, 131072, 65536,
            (void*)Fhh, (void*)Fll, 256, 131072, 0, 1, nullptr, 1.f);

        // 6) G = F * A^T -> f16 pair-packed + diag residual
        mfma_nt<<<dim3(8, 8, 64), 256, 0, stream>>>(
            Fhh, Fll, Ahh, All, 256, 131072, 131072,
            (void*)G, (void*)Gdr, 512, 131072, 512, 2, nullptr, 1.f);

        // 7) 200 ADMM iterations (2-col/thread, 1 barrier/iter)
        solver_2c<<<64, 256, 0, stream>>>(G, Gdr, d0, l, u, ua);

        // 8) x = c0 + Minv A^T u
        finalx_split<<<64, 256, 0, stream>>>(Mh, Ml, c0, ua, A, out);
    } else {
        // ---------------- fallback: R3-style sequence (fits ~64.5 MB) -------
        float*  Mmat = (float*)(ws);
        __half* Fh   = (__half*)(ws);
        float*  Minv = (float*)(ws + (16ull << 20));
        float*  E    = (float*)(ws + (32ull << 20));
        float*  T    = (float*)(ws + (36ull << 20));
        float*  S    = (float*)(ws + (40ull << 20));
        float*  V    = (float*)(ws + (44ull << 20));
        __half* G    = (__half*)(ws + (32ull << 20));
        char*   tail = ws + (64ull << 20);
        float*  c0   = (float*)(tail);
        float*  d0   = (float*)(tail + 65536);
        float*  ua   = (float*)(tail + 196608);
        float*  Gdr  = (float*)(tail + 327680);

        gemm_bt<<<dim3(4, 4, 64), 256, 0, stream>>>(
            A, nullptr, 256, 131072, 1,  A, 256, 131072, 0,
            nullptr, 0, 0,  Mmat, nullptr, 256, 65536,
            RHO_, 0.f, 256, 256, 512, 0, nullptr, 0);
        add_diag<<<64, 256, 0, stream>>>(Mmat, P);
        gj128_blk<<<64, 256, 65536, stream>>>(Mmat, 256, 65536, E, 128, 16384);
        gemm_bt<<<dim3(2, 2, 64), 256, 0, stream>>>(
            Mmat + 128 * 256, nullptr, 256, 65536, 0,  E, 128, 16384, 0,
            nullptr, 0, 0,  T, nullptr, 128, 16384,
            1.f, 0.f, 128, 128, 128, 0, nullptr, 0);
        gemm_bt<<<dim3(2, 2, 64), 256, 0, stream>>>(
            T, nullptr, 128, 16384, 0,  Mmat + 128, 256, 65536, 0,
            Mmat + 128 * 256 + 128, 256, 65536,
            S, nullptr, 128, 16384,
            -1.f, 1.f, 128, 128, 128, 0, nullptr, 0);
        gj128_blk<<<64, 256, 65536, stream>>>(S, 128, 16384, Minv + 128 * 256 + 128, 256, 65536);
        gemm_bt<<<dim3(2, 2, 64), 256, 0, stream>>>(
            Minv + 128 * 256 + 128, nullptr, 256, 65536, 0,  T, 128, 16384, 0,
            nullptr, 0, 0,  V, nullptr, 128, 16384,
            1.f, 0.f, 128, 128, 128, 0, nullptr, 0);
        gemm_bt<<<dim3(2, 2, 64), 256, 0, stream>>>(
            T, nullptr, 128, 16384, 1,  V, 128, 16384, 0,
            E, 128, 16384,
            Minv, nullptr, 256, 65536,
            1.f, 1.f, 128, 128, 128, 0, nullptr, 0);
        assemble_offdiag<<<64, 256, 0, stream>>>(Minv, V);
        c0d0_kernel<<<64, 512, 0, stream>>>(Minv, q, A, c0, d0);
        gemm_bt<<<dim3(4, 8, 64), 256, 0, stream>>>(
            A, nullptr, 256, 131072, 0,  Minv, 256, 65536, 0,
            nullptr, 0, 0,  nullptr, Fh, 256, 131072,
            1.f, 0.f, 512, 256, 256, 0, nullptr, 0);
        gemm_bt<<<dim3(8, 8, 64), 256, 0, stream>>>(
            nullptr, Fh, 256, 131072, 0,  A, 256, 131072, 1,
            nullptr, 0, 0,  nullptr, G, 512, 262144,
            1.f, 0.f, 512, 512, 256, 1, Gdr, 512);
        solver_2c<<<64, 256, 0, stream>>>((const unsigned int*)G, Gdr, d0, l, u, ua);
        finalx<<<64, 256, 0, stream>>>(Minv, c0, ua, A, out);
    }
}

// Round 10
// 785.896 us; speedup vs baseline: 1.6540x; 1.6540x over previous
//
#include <hip/hip_runtime.h>
#include <hip/hip_fp16.h>

// Problem constants (match reference)
#define B_      64
#define N_      256
#define M_      512
#define SIGMA_  1e-6f
#define RHO_    0.1f
#define ALPHA_  1.6f
#define BETA_   (-0.6f)   // 1 - ALPHA
#define ITERS_  200

#if defined(__has_builtin)
#if __has_builtin(__builtin_amdgcn_fdot2)
#define HAVE_FDOT2 1
#endif
#endif

typedef _Float16 h2_t __attribute__((ext_vector_type(2)));

__device__ __forceinline__ float fdot2f(__half2 a, __half2 b, float c) {
#ifdef HAVE_FDOT2
    return __builtin_amdgcn_fdot2(__builtin_bit_cast(h2_t, a),
                                  __builtin_bit_cast(h2_t, b), c, false);
#else
    return c + __low2float(a) * __low2float(b) + __high2float(a) * __high2float(b);
#endif
}

__device__ __forceinline__ float fdot2u(unsigned int a, unsigned int b, float c) {
    return fdot2f(__builtin_bit_cast(__half2, a), __builtin_bit_cast(__half2, b), c);
}

// bf16 round-to-nearest-even helpers
__device__ __forceinline__ unsigned short bf16rne(float f) {
    unsigned int u = __builtin_bit_cast(unsigned int, f);
    u += 0x7fffu + ((u >> 16) & 1u);
    return (unsigned short)(u >> 16);
}
__device__ __forceinline__ float bf16tof(unsigned short h) {
    unsigned int u = ((unsigned int)h) << 16;
    return __builtin_bit_cast(float, u);
}

__device__ __forceinline__ float f4c(const float4& v, int k) {
    return k == 0 ? v.x : k == 1 ? v.y : k == 2 ? v.z : v.w;
}

// ---------------------------------------------------------------------------
// Generic batched tiled GEMM (fp32 VALU) — fallback path only.
// ---------------------------------------------------------------------------
__global__ __launch_bounds__(256) void gemm_bt(
    const float* __restrict__ Af, const __half* __restrict__ Ah, int lda, long long sA, int tA,
    const float* __restrict__ Bf, int ldb, long long sB, int tB,
    const float* __restrict__ Dp, int ldd, long long sD,
    float* __restrict__ Cf, __half* __restrict__ Ch, int ldc, long long sC,
    float alpha, float beta, int Mx, int Nx, int Kx, int packPairs,
    float* __restrict__ Gdr, long long sGdr)
{
    __shared__ float as_[16][68];
    __shared__ float bs_[16][68];

    const int tid = threadIdx.x;
    const int b   = blockIdx.z;
    const int i0  = blockIdx.y * 64;
    const int j0  = blockIdx.x * 64;

    if (Af) Af += (size_t)b * sA;
    if (Ah) Ah += (size_t)b * sA;
    Bf += (size_t)b * sB;
    if (Dp) Dp += (size_t)b * sD;
    if (Cf) Cf += (size_t)b * sC;
    if (Ch) Ch += (size_t)b * sC;
    if (Gdr) Gdr += (size_t)b * sGdr;

    const int ty = tid >> 4;
    const int tx = tid & 15;

    float acc[4][4] = {};

    #pragma unroll 1
    for (int k0 = 0; k0 < Kx; k0 += 16) {
        if (tA) {
            const int kk = tid >> 4, i4 = (tid & 15) << 2;
            float4 v = *(const float4*)(Af + (size_t)(k0 + kk) * lda + i0 + i4);
            *(float4*)&as_[kk][i4] = v;
        } else {
            const int ii = tid >> 2, k4 = (tid & 3) << 2;
            if (Ah) {
                const __half2* hp = (const __half2*)(Ah + (size_t)(i0 + ii) * lda + k0 + k4);
                __half2 h0 = hp[0], h1 = hp[1];
                as_[k4 + 0][ii] = __low2float(h0);
                as_[k4 + 1][ii] = __high2float(h0);
                as_[k4 + 2][ii] = __low2float(h1);
                as_[k4 + 3][ii] = __high2float(h1);
            } else {
                float4 v = *(const float4*)(Af + (size_t)(i0 + ii) * lda + k0 + k4);
                as_[k4 + 0][ii] = v.x; as_[k4 + 1][ii] = v.y;
                as_[k4 + 2][ii] = v.z; as_[k4 + 3][ii] = v.w;
            }
        }
        if (tB) {
            const int jj = tid >> 2, k4 = (tid & 3) << 2;
            float4 v = *(const float4*)(Bf + (size_t)(j0 + jj) * ldb + k0 + k4);
            bs_[k4 + 0][jj] = v.x; bs_[k4 + 1][jj] = v.y;
            bs_[k4 + 2][jj] = v.z; bs_[k4 + 3][jj] = v.w;
        } else {
            const int kk = tid >> 4, j4 = (tid & 15) << 2;
            float4 v = *(const float4*)(Bf + (size_t)(k0 + kk) * ldb + j0 + j4);
            *(float4*)&bs_[kk][j4] = v;
        }
        __syncthreads();

        #pragma unroll
        for (int kk = 0; kk < 16; kk++) {
            float4 av = *(float4*)&as_[kk][ty << 2];
            float4 bv = *(float4*)&bs_[kk][tx << 2];
            acc[0][0] += av.x * bv.x; acc[0][1] += av.x * bv.y;
            acc[0][2] += av.x * bv.z; acc[0][3] += av.x * bv.w;
            acc[1][0] += av.y * bv.x; acc[1][1] += av.y * bv.y;
            acc[1][2] += av.y * bv.z; acc[1][3] += av.y * bv.w;
            acc[2][0] += av.z * bv.x; acc[2][1] += av.z * bv.y;
            acc[2][2] += av.z * bv.z; acc[2][3] += av.z * bv.w;
            acc[3][0] += av.w * bv.x; acc[3][1] += av.w * bv.y;
            acc[3][2] += av.w * bv.z; acc[3][3] += av.w * bv.w;
        }
        __syncthreads();
    }

    if (Ch) {
        if (packPairs) {
            __half2* C2 = (__half2*)Ch;
            const int mrow = i0 + (ty << 2);
            #pragma unroll
            for (int p = 0; p < 2; p++) {
                #pragma unroll
                for (int jj = 0; jj < 4; jj++) {
                    const float v0 = alpha * acc[2 * p][jj];
                    const float v1 = alpha * acc[2 * p + 1][jj];
                    __half2 h = __floats2half2_rn(v0, v1);
                    C2[(size_t)((mrow >> 1) + p) * ldc + j0 + (tx << 2) + jj] = h;
                    if (Gdr) {
                        const int col = j0 + (tx << 2) + jj;
                        const int r0  = mrow + 2 * p;
                        if (col == r0)          Gdr[col] = v0 - __low2float(h);
                        else if (col == r0 + 1) Gdr[col] = v1 - __high2float(h);
                    }
                }
            }
        } else {
            #pragma unroll
            for (int ii = 0; ii < 4; ii++) {
                #pragma unroll
                for (int jj = 0; jj < 4; jj++) {
                    Ch[(size_t)(i0 + (ty << 2) + ii) * ldc + j0 + (tx << 2) + jj] =
                        __float2half_rn(alpha * acc[ii][jj]);
                }
            }
        }
    } else {
        #pragma unroll
        for (int ii = 0; ii < 4; ii++) {
            const int m = i0 + (ty << 2) + ii;
            const int n = j0 + (tx << 2);
            float4 v;
            v.x = alpha * acc[ii][0]; v.y = alpha * acc[ii][1];
            v.z = alpha * acc[ii][2]; v.w = alpha * acc[ii][3];
            if (Dp) {
                float4 d = *(const float4*)(Dp + (size_t)m * ldd + n);
                v.x += beta * d.x; v.y += beta * d.y;
                v.z += beta * d.z; v.w += beta * d.w;
            }
            *(float4*)(Cf + (size_t)m * ldc + n) = v;
        }
    }
}

// ---------------------------------------------------------------------------
// MFMA split-bf16 GEMM with LDS-staged Y operand:  C = X · Y^T. (R8-verified)
// ---------------------------------------------------------------------------
typedef __attribute__((ext_vector_type(8))) short bfrag;
typedef __attribute__((ext_vector_type(4))) float ffrag;

__global__ __launch_bounds__(256) void mfma_nt(
    const unsigned short* __restrict__ Xh, const unsigned short* __restrict__ Xl,
    const unsigned short* __restrict__ Yh, const unsigned short* __restrict__ Yl,
    int Kx, long long sX, long long sY,
    void* __restrict__ out0, void* __restrict__ out1,
    int ldc, long long sC, long long sC2, int mode,
    const float* __restrict__ Pd, float alpha)
{
    __shared__ unsigned short Ysh[2][64][264];

    const int tid = threadIdx.x;
    const int w   = tid >> 6;
    const int l   = tid & 63;
    const int b   = blockIdx.z;
    const int rowbase = blockIdx.y * 64 + w * 16;
    const int colbase = blockIdx.x * 64;
    const int lr = l & 15;
    const int q  = l >> 4;

    const unsigned short* xh = Xh + (size_t)b * sX + (size_t)(rowbase + lr) * Kx + q * 8;
    const unsigned short* xl = Xl + (size_t)b * sX + (size_t)(rowbase + lr) * Kx + q * 8;
    const unsigned short* ybh = Yh + (size_t)b * sY;
    const unsigned short* ybl = Yl + (size_t)b * sY;

    ffrag acc[4] = {};

    #pragma unroll 1
    for (int kc = 0; kc < Kx; kc += 256) {
        __syncthreads();
        #pragma unroll
        for (int e = 0; e < 8; e++) {
            const int idx = e * 256 + tid;
            const int c  = idx >> 5;
            const int kq = idx & 31;
            const size_t so = (size_t)(colbase + c) * Kx + kc + kq * 8;
            *(uint4*)&Ysh[0][c][kq * 8] = *(const uint4*)(ybh + so);
            *(uint4*)&Ysh[1][c][kq * 8] = *(const uint4*)(ybl + so);
        }
        __syncthreads();

        #pragma unroll 2
        for (int k0 = kc; k0 < kc + 256; k0 += 32) {
            bfrag ah = *(const bfrag*)(xh + k0);
            bfrag al = *(const bfrag*)(xl + k0);
            const int ko = (k0 - kc) + q * 8;
            #pragma unroll
            for (int t = 0; t < 4; t++) {
                bfrag bh = *(const bfrag*)&Ysh[0][16 * t + lr][ko];
                bfrag bl = *(const bfrag*)&Ysh[1][16 * t + lr][ko];
                acc[t] = __builtin_amdgcn_mfma_f32_16x16x32_bf16(ah, bh, acc[t], 0, 0, 0);
                acc[t] = __builtin_amdgcn_mfma_f32_16x16x32_bf16(ah, bl, acc[t], 0, 0, 0);
                acc[t] = __builtin_amdgcn_mfma_f32_16x16x32_bf16(al, bh, acc[t], 0, 0, 0);
            }
        }
    }

    if (mode == 0) {
        float* Cf = (float*)out0 + (size_t)b * sC;
        #pragma unroll
        for (int t = 0; t < 4; t++) {
            #pragma unroll
            for (int p = 0; p < 4; p++) {
                const int r  = rowbase + q * 4 + p;
                const int cc = colbase + 16 * t + lr;
                float v = alpha * acc[t][p];
                if (Pd && cc == r) v += Pd[b * 256 + r] + SIGMA_;
                Cf[(size_t)r * ldc + cc] = v;
            }
        }
    } else if (mode == 1) {
        unsigned short* Fh = (unsigned short*)out0 + (size_t)b * sC;
        unsigned short* Fl = (unsigned short*)out1 + (size_t)b * sC;
        #pragma unroll
        for (int t = 0; t < 4; t++) {
            #pragma unroll
            for (int p = 0; p < 4; p++) {
                const int r  = rowbase + q * 4 + p;
                const int cc = colbase + 16 * t + lr;
                const float v = acc[t][p];
                const unsigned short hh = bf16rne(v);
                Fh[(size_t)r * ldc + cc] = hh;
                Fl[(size_t)r * ldc + cc] = bf16rne(v - bf16tof(hh));
            }
        }
    } else {
        unsigned int* Gpp = (unsigned int*)out0 + (size_t)b * sC;
        float* Gd = (float*)out1 + (size_t)b * sC2;
        #pragma unroll
        for (int t = 0; t < 4; t++) {
            #pragma unroll
            for (int p2 = 0; p2 < 2; p2++) {
                const int r0 = rowbase + q * 4 + 2 * p2;
                const int cc = colbase + 16 * t + lr;
                const float v0 = acc[t][2 * p2], v1 = acc[t][2 * p2 + 1];
                __half2 h = __floats2half2_rn(v0, v1);
                Gpp[(size_t)(r0 >> 1) * ldc + cc] = __builtin_bit_cast(unsigned int, h);
                if (cc == r0)          Gd[cc] = v0 - __low2float(h);
                else if (cc == r0 + 1) Gd[cc] = v1 - __high2float(h);
            }
        }
    }
}

// ---------------------------------------------------------------------------
// prep_a: A -> AT split-bf16 and A split-bf16 in one pass (R8-verified)
// ---------------------------------------------------------------------------
__global__ __launch_bounds__(256) void prep_a(
    const float* __restrict__ A, unsigned short* __restrict__ Th,
    unsigned short* __restrict__ Tl, unsigned short* __restrict__ Ahh,
    unsigned short* __restrict__ All)
{
    __shared__ float t_[64][65];
    const int b  = blockIdx.z;
    const int r0 = blockIdx.x * 64;
    const int c0 = blockIdx.y * 64;
    const int tid = threadIdx.x;
    const int ty = tid >> 4, tx = tid & 15;
    const float* Ab = A + (size_t)b * 131072;
    unsigned short* Ahb = Ahh + (size_t)b * 131072;
    unsigned short* Alb = All + (size_t)b * 131072;

    #pragma unroll
    for (int p = 0; p < 4; p++) {
        const int rr = ty + p * 16;
        const size_t o = (size_t)(r0 + rr) * 256 + c0 + tx * 4;
        float4 v = *(const float4*)(Ab + o);
        t_[rr][tx * 4 + 0] = v.x; t_[rr][tx * 4 + 1] = v.y;
        t_[rr][tx * 4 + 2] = v.z; t_[rr][tx * 4 + 3] = v.w;
        unsigned short h0 = bf16rne(v.x), h1 = bf16rne(v.y);
        unsigned short h2 = bf16rne(v.z), h3 = bf16rne(v.w);
        uint2 hp, lp;
        hp.x = (unsigned int)h0 | ((unsigned int)h1 << 16);
        hp.y = (unsigned int)h2 | ((unsigned int)h3 << 16);
        lp.x = (unsigned int)bf16rne(v.x - bf16tof(h0)) |
               ((unsigned int)bf16rne(v.y - bf16tof(h1)) << 16);
        lp.y = (unsigned int)bf16rne(v.z - bf16tof(h2)) |
               ((unsigned int)bf16rne(v.w - bf16tof(h3)) << 16);
        *(uint2*)(Ahb + o) = hp;
        *(uint2*)(Alb + o) = lp;
    }
    __syncthreads();

    unsigned short* Thb = Th + (size_t)b * 131072;
    unsigned short* Tlb = Tl + (size_t)b * 131072;
    #pragma unroll
    for (int p = 0; p < 4; p++) {
        const int ar = ty + p * 16;
        unsigned int hp[2], lp[2];
        #pragma unroll
        for (int d2 = 0; d2 < 2; d2++) {
            unsigned short h0, h1, l0, l1;
            {
                const float v = t_[tx * 4 + 2 * d2][ar];
                h0 = bf16rne(v); l0 = bf16rne(v - bf16tof(h0));
            }
            {
                const float v = t_[tx * 4 + 2 * d2 + 1][ar];
                h1 = bf16rne(v); l1 = bf16rne(v - bf16tof(h1));
            }
            hp[d2] = (unsigned int)h0 | ((unsigned int)h1 << 16);
            lp[d2] = (unsigned int)l0 | ((unsigned int)l1 << 16);
        }
        const size_t o = (size_t)(c0 + ar) * 512 + r0 + tx * 4;
        *(uint2*)(Thb + o) = make_uint2(hp[0], hp[1]);
        *(uint2*)(Tlb + o) = make_uint2(lp[0], lp[1]);
    }
}

// ---------------------------------------------------------------------------
// Mmat diag add (fallback path only)
// ---------------------------------------------------------------------------
__global__ void add_diag(float* __restrict__ Mm, const float* __restrict__ P)
{
    const int b = blockIdx.x, t = threadIdx.x;
    Mm[(size_t)b * 65536 + (size_t)t * 257] += P[b * 256 + t] + SIGMA_;
}

// ---------------------------------------------------------------------------
// XOR-quad swizzled 128x128 LDS matrix layout helpers
// ---------------------------------------------------------------------------
__device__ __forceinline__ int gja(int i, int j)
{
    return (i << 7) + ((((j >> 2) ^ (i & 31)) << 2) | (j & 3));
}
__device__ __forceinline__ float4 ldsq(const float* Mp, int row, int q)
{
    return *(const float4*)&Mp[(row << 7) + (((q ^ (row & 31)) << 2))];
}
__device__ __forceinline__ void stsq(float* Mp, int row, int q, float4 v)
{
    *(float4*)&Mp[(row << 7) + (((q ^ (row & 31)) << 2))] = v;
}

// ---------------------------------------------------------------------------
// Rank-16 blocked Gauss-Jordan on a 128x128 SPD matrix in LDS (R7-verified).
// ---------------------------------------------------------------------------
__device__ void gj_lds(float* Msh, float (&Dsh)[16][17], float (&CT)[16][136],
                       float (&RS)[16][136], float (&CDs)[16][136],
                       float (&rowB)[2][16], float (&colB)[2][16], float (&pB)[2],
                       int tid)
{
    const int di = tid >> 4;
    const int dj = tid & 15;

    #pragma unroll 1
    for (int t = 0; t < 8; t++) {
        const int tb = t << 4;

        float a = Msh[gja(tb + di, tb + dj)];
        #pragma unroll
        for (int g2 = 0; g2 < 2; g2++) {
            const int i0 = (dj << 2) + (g2 << 6);
            float4 cv;
            if ((i0 >> 4) == t) {
                cv.x = 0.f; cv.y = 0.f; cv.z = 0.f; cv.w = 0.f;
            } else {
                cv.x = Msh[gja(i0 + 0, tb + di)];
                cv.y = Msh[gja(i0 + 1, tb + di)];
                cv.z = Msh[gja(i0 + 2, tb + di)];
                cv.w = Msh[gja(i0 + 3, tb + di)];
            }
            *(float4*)&CT[di][i0] = cv;
        }
        __syncthreads();

        #pragma unroll 1
        for (int k = 0; k < 16; k++) {
            const int kb = k & 1;
            if (dj == k) colB[kb][di] = a;
            if (di == k) {
                rowB[kb][dj] = a;
                if (dj == k) pB[kb] = 1.0f / a;
            }
            __syncthreads();
            const float ip = pB[kb];
            const float rj = rowB[kb][dj];
            const float ci = colB[kb][di];
            if (di == k)      a = (dj == k) ? ip : rj * ip;
            else if (dj == k) a = -ci * ip;
            else              a -= ci * (rj * ip);
        }
        Dsh[di][dj] = a;
        __syncthreads();

        #pragma unroll
        for (int g2 = 0; g2 < 2; g2++) {
            const int j = (dj << 2) + (g2 << 6);
            float4 s; s.x = 0.f; s.y = 0.f; s.z = 0.f; s.w = 0.f;
            if ((j >> 4) != t) {
                #pragma unroll
                for (int m = 0; m < 16; m++) {
                    const float d = Dsh[di][m];
                    const float4 rv = ldsq(Msh, tb + m, j >> 2);
                    s.x += d * rv.x; s.y += d * rv.y;
                    s.z += d * rv.z; s.w += d * rv.w;
                }
            }
            *(float4*)&RS[di][j] = s;

            float4 sc; sc.x = 0.f; sc.y = 0.f; sc.z = 0.f; sc.w = 0.f;
            #pragma unroll
            for (int m = 0; m < 16; m++) {
                const float d = Dsh[m][di];
                const float4 cv = *(const float4*)&CT[m][j];
                sc.x += d * cv.x; sc.y += d * cv.y;
                sc.z += d * cv.z; sc.w += d * cv.w;
            }
            *(float4*)&CDs[di][j] = sc;
        }
        __syncthreads();

        {
            const int ty = di, tx = dj;
            float4 v0[8], v1[8];
            int cofs0[8], cofs1[8];
            #pragma unroll
            for (int r = 0; r < 8; r++) {
                const int i = (ty << 3) + r;
                const int e = i & 31;
                const int base = i << 7;
                cofs0[r] = base + ((((tx << 1)     ) ^ e) << 2);
                cofs1[r] = base + ((((tx << 1) | 1 ) ^ e) << 2);
                v0[r] = *(float4*)&Msh[cofs0[r]];
                v1[r] = *(float4*)&Msh[cofs1[r]];
            }
            #pragma unroll 1
            for (int k = 0; k < 16; k++) {
                const float4 r0 = *(const float4*)&RS[k][tx << 3];
                const float4 r1 = *(const float4*)&RS[k][(tx << 3) + 4];
                const float4 c0 = *(const float4*)&CT[k][ty << 3];
                const float4 c1 = *(const float4*)&CT[k][(ty << 3) + 4];
                const float cc[8] = {c0.x, c0.y, c0.z, c0.w,
                                     c1.x, c1.y, c1.z, c1.w};
                #pragma unroll
                for (int r = 0; r < 8; r++) {
                    const float c = cc[r];
                    v0[r].x -= c * r0.x; v0[r].y -= c * r0.y;
                    v0[r].z -= c * r0.z; v0[r].w -= c * r0.w;
                    v1[r].x -= c * r1.x; v1[r].y -= c * r1.y;
                    v1[r].z -= c * r1.z; v1[r].w -= c * r1.w;
                }
            }
            #pragma unroll
            for (int r = 0; r < 8; r++) {
                *(float4*)&Msh[cofs0[r]] = v0[r];
                *(float4*)&Msh[cofs1[r]] = v1[r];
            }
        }
        __syncthreads();

        #pragma unroll
        for (int g2 = 0; g2 < 2; g2++) {
            const int j = (dj << 2) + (g2 << 6);
            if ((j >> 4) != t) {
                stsq(Msh, tb + di, j >> 2, *(const float4*)&RS[di][j]);
                const float4 cd = *(const float4*)&CDs[di][j];
                Msh[gja(j + 0, tb + di)] = -cd.x;
                Msh[gja(j + 1, tb + di)] = -cd.y;
                Msh[gja(j + 2, tb + di)] = -cd.z;
                Msh[gja(j + 3, tb + di)] = -cd.w;
            }
        }
        Msh[gja(tb + di, tb + dj)] = Dsh[di][dj];
        __syncthreads();
    }
}

// ---------------------------------------------------------------------------
// gj128_blk — standalone kernel (fallback path)
// ---------------------------------------------------------------------------
__global__ __launch_bounds__(256) void gj128_blk(
    const float* __restrict__ src, int lsrc, long long ssrc,
    float* __restrict__ dst, int ldst, long long sdst)
{
    extern __shared__ float Msh[];
    __shared__ float Dsh[16][17];
    __shared__ float CT[16][136];
    __shared__ float RS[16][136];
    __shared__ float CDs[16][136];
    __shared__ float rowB[2][16], colB[2][16], pB[2];

    const int tid = threadIdx.x, b = blockIdx.x;
    src += (size_t)b * ssrc;
    dst += (size_t)b * sdst;

    for (int qd = 0; qd < 64; qd++) {
        const int idx = qd * 256 + tid;
        const int i = idx >> 7, j = idx & 127;
        Msh[gja(i, j)] = src[(size_t)i * lsrc + j];
    }
    __syncthreads();
    gj_lds(Msh, Dsh, CT, RS, CDs, rowB, colB, pB, tid);
    for (int qd = 0; qd < 64; qd++) {
        const int idx = qd * 256 + tid;
        const int i = idx >> 7, j = idx & 127;
        dst[(size_t)i * ldst + j] = Msh[gja(i, j)];
    }
}

// ---------------------------------------------------------------------------
// schur_inv: full Schur-complement inversion chain, one kernel (R8-verified).
// ---------------------------------------------------------------------------
__global__ __launch_bounds__(256) void schur_inv(
    const float* __restrict__ Mmat, float* __restrict__ Ebuf,
    float* __restrict__ Minv, unsigned short* __restrict__ Mh,
    unsigned short* __restrict__ Ml)
{
    __shared__ float A1[16384];
    __shared__ float A2[16384];
    __shared__ float Dsh[16][17];
    __shared__ float CT[16][136];
    __shared__ float RS[16][136];
    __shared__ float CDs[16][136];
    __shared__ float rowB[2][16], colB[2][16], pB[2];

    const int tid = threadIdx.x, b = blockIdx.x;
    const float* Mb = Mmat + (size_t)b * 65536;
    float* Eb = Ebuf + (size_t)b * 16384;
    float* Ib = Minv + (size_t)b * 65536;
    unsigned short* Mhb = Mh + (size_t)b * 65536;
    unsigned short* Mlb = Ml + (size_t)b * 65536;

    const int ty = tid >> 4, tx = tid & 15;

    for (int qd = 0; qd < 64; qd++) {
        const int idx = qd * 256 + tid;
        const int i = idx >> 7, j = idx & 127;
        A1[gja(i, j)] = Mb[(size_t)i * 256 + j];
    }
    __syncthreads();
    gj_lds(A1, Dsh, CT, RS, CDs, rowB, colB, pB, tid);

    for (int qd = 0; qd < 64; qd++) {
        const int idx = qd * 256 + tid;
        const int i = idx >> 7, j = idx & 127;
        Eb[(size_t)i * 128 + j] = A1[gja(i, j)];
        A2[gja(i, j)] = Mb[(size_t)(128 + i) * 256 + j];
    }
    __syncthreads();

    // T = M21 * E (in-place A2)
    {
        float acc[8][8] = {};
        #pragma unroll 1
        for (int k4 = 0; k4 < 32; k4++) {
            float4 mq[8];
            #pragma unroll
            for (int r = 0; r < 8; r++) mq[r] = ldsq(A2, 8 * ty + r, k4);
            #pragma unroll
            for (int kk = 0; kk < 4; kk++) {
                const int k = k4 * 4 + kk;
                const float4 e0 = ldsq(A1, k, 2 * tx);
                const float4 e1 = ldsq(A1, k, 2 * tx + 1);
                const float ev[8] = {e0.x, e0.y, e0.z, e0.w, e1.x, e1.y, e1.z, e1.w};
                #pragma unroll
                for (int r = 0; r < 8; r++) {
                    const float m = f4c(mq[r], kk);
                    #pragma unroll
                    for (int c = 0; c < 8; c++) acc[r][c] += m * ev[c];
                }
            }
        }
        __syncthreads();
        #pragma unroll
        for (int r = 0; r < 8; r++) {
            float4 o0, o1;
            o0.x = acc[r][0]; o0.y = acc[r][1]; o0.z = acc[r][2]; o0.w = acc[r][3];
            o1.x = acc[r][4]; o1.y = acc[r][5]; o1.z = acc[r][6]; o1.w = acc[r][7];
            stsq(A2, 8 * ty + r, 2 * tx, o0);
            stsq(A2, 8 * ty + r, 2 * tx + 1, o1);
        }
        __syncthreads();
    }

    // S = M22 - T * M12 -> A1
    {
        float acc[8][8];
        #pragma unroll
        for (int r = 0; r < 8; r++) {
            const float4 a0 = *(const float4*)&Mb[(size_t)(128 + 8 * ty + r) * 256 + 128 + 8 * tx];
            const float4 a1 = *(const float4*)&Mb[(size_t)(128 + 8 * ty + r) * 256 + 128 + 8 * tx + 4];
            acc[r][0] = a0.x; acc[r][1] = a0.y; acc[r][2] = a0.z; acc[r][3] = a0.w;
            acc[r][4] = a1.x; acc[r][5] = a1.y; acc[r][6] = a1.z; acc[r][7] = a1.w;
        }
        #pragma unroll 1
        for (int kt = 0; kt < 8; kt++) {
            __syncthreads();
            #pragma unroll
            for (int e = 0; e < 8; e++) {
                const int idx = e * 256 + tid;
                const int kk = idx >> 7, j = idx & 127;
                RS[kk][j] = Mb[(size_t)(kt * 16 + kk) * 256 + 128 + j];
            }
            __syncthreads();
            #pragma unroll 1
            for (int k2 = 0; k2 < 16; k2 += 4) {
                const int kq = (kt * 16 + k2) >> 2;
                float4 tq[8];
                #pragma unroll
                for (int r = 0; r < 8; r++) tq[r] = ldsq(A2, 8 * ty + r, kq);
                #pragma unroll
                for (int kk = 0; kk < 4; kk++) {
                    const float4 m0 = *(const float4*)&RS[k2 + kk][8 * tx];
                    const float4 m1 = *(const float4*)&RS[k2 + kk][8 * tx + 4];
                    const float mv[8] = {m0.x, m0.y, m0.z, m0.w, m1.x, m1.y, m1.z, m1.w};
                    #pragma unroll
                    for (int r = 0; r < 8; r++) {
                        const float t2 = f4c(tq[r], kk);
                        #pragma unroll
                        for (int c = 0; c < 8; c++) acc[r][c] -= t2 * mv[c];
                    }
                }
            }
        }
        __syncthreads();
        #pragma unroll
        for (int r = 0; r < 8; r++) {
            float4 o0, o1;
            o0.x = acc[r][0]; o0.y = acc[r][1]; o0.z = acc[r][2]; o0.w = acc[r][3];
            o1.x = acc[r][4]; o1.y = acc[r][5]; o1.z = acc[r][6]; o1.w = acc[r][7];
            stsq(A1, 8 * ty + r, 2 * tx, o0);
            stsq(A1, 8 * ty + r, 2 * tx + 1, o1);
        }
        __syncthreads();
    }

    gj_lds(A1, Dsh, CT, RS, CDs, rowB, colB, pB, tid);
    for (int qd = 0; qd < 64; qd++) {
        const int idx = qd * 256 + tid;
        const int i = idx >> 7, j = idx & 127;
        const float v = A1[gja(i, j)];
        const size_t o = (size_t)(128 + i) * 256 + 128 + j;
        Ib[o] = v;
        const unsigned short hh = bf16rne(v);
        Mhb[o] = hh; Mlb[o] = bf16rne(v - bf16tof(hh));
    }

    // V = Sinv * T (in-place A1)
    {
        float acc[8][8] = {};
        #pragma unroll 1
        for (int k4 = 0; k4 < 32; k4++) {
            float4 sq[8];
            #pragma unroll
            for (int r = 0; r < 8; r++) sq[r] = ldsq(A1, 8 * ty + r, k4);
            #pragma unroll
            for (int kk = 0; kk < 4; kk++) {
                const int k = k4 * 4 + kk;
                const float4 t0 = ldsq(A2, k, 2 * tx);
                const float4 t1 = ldsq(A2, k, 2 * tx + 1);
                const float tv[8] = {t0.x, t0.y, t0.z, t0.w, t1.x, t1.y, t1.z, t1.w};
                #pragma unroll
                for (int r = 0; r < 8; r++) {
                    const float m = f4c(sq[r], kk);
                    #pragma unroll
                    for (int c = 0; c < 8; c++) acc[r][c] += m * tv[c];
                }
            }
        }
        __syncthreads();
        #pragma unroll
        for (int r = 0; r < 8; r++) {
            float4 o0, o1;
            o0.x = acc[r][0]; o0.y = acc[r][1]; o0.z = acc[r][2]; o0.w = acc[r][3];
            o1.x = acc[r][4]; o1.y = acc[r][5]; o1.z = acc[r][6]; o1.w = acc[r][7];
            stsq(A1, 8 * ty + r, 2 * tx, o0);
            stsq(A1, 8 * ty + r, 2 * tx + 1, o1);
        }
        __syncthreads();
    }

    for (int qd = 0; qd < 64; qd++) {
        const int idx = qd * 256 + tid;
        const int i = idx >> 7, j = idx & 127;
        const float v = -A1[gja(i, j)];
        const size_t o = (size_t)(128 + i) * 256 + j;
        Ib[o] = v;
        const unsigned short hh = bf16rne(v);
        Mhb[o] = hh; Mlb[o] = bf16rne(v - bf16tof(hh));
    }
    for (int qd = 0; qd < 64; qd++) {
        const int idx = qd * 256 + tid;
        const int j = idx >> 7, i = idx & 127;
        const float v = -A1[gja(i, j)];
        const size_t o = (size_t)j * 256 + 128 + i;
        Ib[o] = v;
        const unsigned short hh = bf16rne(v);
        Mhb[o] = hh; Mlb[o] = bf16rne(v - bf16tof(hh));
    }

    // Minv11 = E + T^T * V
    {
        float acc[8][8] = {};
        #pragma unroll 1
        for (int k = 0; k < 128; k++) {
            const float4 t0 = ldsq(A2, k, 2 * ty);
            const float4 t1 = ldsq(A2, k, 2 * ty + 1);
            const float4 v0 = ldsq(A1, k, 2 * tx);
            const float4 v1 = ldsq(A1, k, 2 * tx + 1);
            const float tv[8] = {t0.x, t0.y, t0.z, t0.w, t1.x, t1.y, t1.z, t1.w};
            const float vv[8] = {v0.x, v0.y, v0.z, v0.w, v1.x, v1.y, v1.z, v1.w};
            #pragma unroll
            for (int r = 0; r < 8; r++)
                #pragma unroll
                for (int c = 0; c < 8; c++) acc[r][c] += tv[r] * vv[c];
        }
        #pragma unroll
        for (int r = 0; r < 8; r++) {
            const float4 e0 = *(const float4*)&Eb[(size_t)(8 * ty + r) * 128 + 8 * tx];
            const float4 e1 = *(const float4*)&Eb[(size_t)(8 * ty + r) * 128 + 8 * tx + 4];
            const float ev[8] = {e0.x, e0.y, e0.z, e0.w, e1.x, e1.y, e1.z, e1.w};
            #pragma unroll
            for (int c = 0; c < 8; c++) {
                const float v = acc[r][c] + ev[c];
                const size_t o = (size_t)(8 * ty + r) * 256 + 8 * tx + c;
                Ib[o] = v;
                const unsigned short hh = bf16rne(v);
                Mhb[o] = hh; Mlb[o] = bf16rne(v - bf16tof(hh));
            }
        }
    }
}

// ---------------------------------------------------------------------------
// Minv off-diagonal blocks (fallback path)
// ---------------------------------------------------------------------------
__global__ void assemble_offdiag(float* __restrict__ Minv, const float* __restrict__ V)
{
    const int b = blockIdx.x, tid = threadIdx.x;
    const float* Vb = V + (size_t)b * 16384;
    float* Mb = Minv + (size_t)b * 65536;
    for (int qd = 0; qd < 64; qd++) {
        const int idx = qd * 256 + tid;
        const int i = idx >> 7, j = idx & 127;
        const float v = -Vb[idx];
        Mb[(size_t)(128 + i) * 256 + j] = v;
        Mb[(size_t)j * 256 + 128 + i]   = v;
    }
}

// ---------------------------------------------------------------------------
// c0 = -Minv q ; d0 = A c0
// ---------------------------------------------------------------------------
__global__ __launch_bounds__(512) void c0d0_kernel(
    const float* __restrict__ Minv, const float* __restrict__ q,
    const float* __restrict__ A, float* __restrict__ c0, float* __restrict__ d0)
{
    __shared__ float qs[256], c0s[256];
    const int b = blockIdx.x, tid = threadIdx.x;
    const float* Mb = Minv + (size_t)b * 65536;

    if (tid < 256) qs[tid] = q[b * 256 + tid];
    __syncthreads();
    if (tid < 256) {
        float acc = 0.f;
        for (int j = 0; j < 256; j++)
            acc += Mb[(size_t)j * 256 + tid] * qs[j];
        c0s[tid] = -acc;
        c0[b * 256 + tid] = -acc;
    }
    __syncthreads();

    const int wid = tid >> 6, lane = tid & 63;
    const float* Ab = A + (size_t)b * 131072;
    for (int m = wid; m < 512; m += 8) {
        float4 a4 = *(const float4*)(Ab + (size_t)m * 256 + (lane << 2));
        float4 c4 = *(const float4*)&c0s[lane << 2];
        float acc = a4.x * c4.x + a4.y * c4.y + a4.z * c4.z + a4.w * c4.w;
        for (int off = 32; off > 0; off >>= 1) acc += __shfl_down(acc, off, 64);
        if (lane == 0) d0[b * 512 + m] = acc;
    }
}

// ---------------------------------------------------------------------------
// ADMM solver (R7-verified config — 283 µs): ONE block per batch, 512 thr,
// 2 waves/SIMD. G split: jj[0,64) in LDS 128 KiB (verbatim conflict-free);
// jj[64,256) register-cached 48 uint4/thread (192 regs -> AGPR file; total
// ~232/256 per-wave budget. gc[56]+ SPILLS — measured R8/R9. Do not raise.)
// ---------------------------------------------------------------------------
__global__ __launch_bounds__(512, 2) void solver_reg(
    const unsigned int* __restrict__ Gp,
    const float* __restrict__ Gdr,
    const float* __restrict__ d0g,
    const float* __restrict__ lg, const float* __restrict__ ug,
    float* __restrict__ uout)
{
    __shared__ unsigned int Gsh[32768];    // jj 0..63, 128 KiB
    __shared__ float part[4][512];
    __shared__ unsigned int rp_sh[256];

    const int tid = threadIdx.x;
    const int b   = blockIdx.x;
    const int g   = tid >> 7;              // group [0,4)
    const int iq  = tid & 127;             // column quad [0,128)

    const unsigned int* Gb = Gp + (size_t)b * 131072;

    {
        const uint4* src4 = (const uint4*)Gb;
        uint4* dst4 = (uint4*)Gsh;
        #pragma unroll
        for (int n = 0; n < 16; n++)
            dst4[n * 512 + tid] = src4[n * 512 + tid];
    }

    const uint4* gb4 = (const uint4*)Gb + (size_t)(64 + 48 * g) * 128 + iq;
    uint4 gc[48];
    #pragma unroll
    for (int d = 0; d < 48; d++) gc[d] = gb4[(size_t)d * 128];

    const float d0v  = d0g[b * 512 + tid];
    const float lv   = lg[b * 512 + tid];
    const float uv   = ug[b * 512 + tid];
    const float gdrv = Gdr[b * 512 + tid];
    float z = 0.f, y = 0.f, ua = 0.f;

    const unsigned int* lbase = Gsh + (g << 13) + (iq << 2);  // (16g*512 + 4iq)

    __syncthreads();

    #pragma unroll 1
    for (int it = 0; it < ITERS_; it++) {
        const float rv = RHO_ * z - y;
        ua = BETA_ * ua + ALPHA_ * rv;
        const float rv2 = __shfl_xor(rv, 1);
        if (!(tid & 1))
            rp_sh[tid >> 1] =
                __builtin_bit_cast(unsigned int, __floats2half2_rn(rv, rv2));
        __syncthreads();

        float a0 = 0.f, a1 = 0.f, a2 = 0.f, a3 = 0.f;
        #pragma unroll
        for (int k = 0; k < 16; k++) {
            uint4 gv = *(const uint4*)(lbase + (k << 9));
            const unsigned int r = rp_sh[(g << 4) + k];
            a0 = fdot2u(gv.x, r, a0); a1 = fdot2u(gv.y, r, a1);
            a2 = fdot2u(gv.z, r, a2); a3 = fdot2u(gv.w, r, a3);
        }
        #pragma unroll
        for (int k = 0; k < 48; k++) {
            const unsigned int r = rp_sh[64 + 48 * g + k];
            a0 = fdot2u(gc[k].x, r, a0); a1 = fdot2u(gc[k].y, r, a1);
            a2 = fdot2u(gc[k].z, r, a2); a3 = fdot2u(gc[k].w, r, a3);
        }
        {
            float4 pv; pv.x = a0; pv.y = a1; pv.z = a2; pv.w = a3;
            *(float4*)&part[g][iq << 2] = pv;
        }
        __syncthreads();

        float sum = part[0][tid] + part[1][tid] + part[2][tid] + part[3][tid];
        const float rv_ = RHO_ * z - y;
        const float zt = d0v + sum + gdrv * rv_;
        const float zr = ALPHA_ * zt + (1.0f - ALPHA_) * z;
        const float w  = zr + y * (1.0f / RHO_);
        const float zn = fminf(fmaxf(w, lv), uv);
        y = RHO_ * (w - zn);
        z = zn;
    }

    uout[b * 512 + tid] = ua;
}

// ---------------------------------------------------------------------------
// x = c0 + Minv (A^T u)  — fp32 Minv (fallback)
// ---------------------------------------------------------------------------
__global__ __launch_bounds__(256) void finalx(
    const float* __restrict__ Minv, const float* __restrict__ c0,
    const float* __restrict__ uacc, const float* __restrict__ A,
    float* __restrict__ out)
{
    __shared__ float us2[512], t1s[256];
    const int b = blockIdx.x, tid = threadIdx.x;

    us2[tid]       = uacc[b * 512 + tid];
    us2[tid + 256] = uacc[b * 512 + 256 + tid];
    __syncthreads();

    const float* Ab = A + (size_t)b * 131072;
    float acc = 0.f;
    for (int m = 0; m < 512; m++)
        acc += Ab[(size_t)m * 256 + tid] * us2[m];
    t1s[tid] = acc;
    __syncthreads();

    const float* Mb = Minv + (size_t)b * 65536;
    float x = c0[b * 256 + tid];
    for (int j = 0; j < 256; j++)
        x += Mb[(size_t)j * 256 + tid] * t1s[j];
    out[b * 256 + tid] = x;
}

// ---------------------------------------------------------------------------
// x = c0 + (Mh+Ml) (A^T u)  — split-bf16 Minv (full path)
// ---------------------------------------------------------------------------
__global__ __launch_bounds__(256) void finalx_split(
    const unsigned short* __restrict__ Mh, const unsigned short* __restrict__ Ml,
    const float* __restrict__ c0, const float* __restrict__ uacc,
    const float* __restrict__ A, float* __restrict__ out)
{
    __shared__ float us2[512], t1s[256];
    const int b = blockIdx.x, tid = threadIdx.x;

    us2[tid]       = uacc[b * 512 + tid];
    us2[tid + 256] = uacc[b * 512 + 256 + tid];
    __syncthreads();

    const float* Ab = A + (size_t)b * 131072;
    float acc = 0.f;
    for (int m = 0; m < 512; m++)
        acc += Ab[(size_t)m * 256 + tid] * us2[m];
    t1s[tid] = acc;
    __syncthreads();

    const unsigned short* Mhb = Mh + (size_t)b * 65536;
    const unsigned short* Mlb = Ml + (size_t)b * 65536;
    float x = c0[b * 256 + tid];
    for (int j = 0; j < 256; j++) {
        const float m = bf16tof(Mhb[(size_t)j * 256 + tid]) +
                        bf16tof(Mlb[(size_t)j * 256 + tid]);
        x += m * t1s[j];
    }
    out[b * 256 + tid] = x;
}

// ---------------------------------------------------------------------------
// Host launcher
// ---------------------------------------------------------------------------
extern "C" void kernel_launch(void* const* d_in, const int* in_sizes, int n_in,
                              void* d_out, int out_size, void* d_ws, size_t ws_size,
                              hipStream_t stream)
{
    (void)in_sizes; (void)n_in; (void)out_size;

    const float* P = (const float*)d_in[0];
    const float* q = (const float*)d_in[1];
    const float* A = (const float*)d_in[2];
    const float* l = (const float*)d_in[3];
    const float* u = (const float*)d_in[4];
    float* out = (float*)d_out;
    char* ws = (char*)d_ws;

    (void)hipFuncSetAttribute(reinterpret_cast<const void*>(&gj128_blk),
                              hipFuncAttributeMaxDynamicSharedMemorySize, 65536);

    const bool fullPath = (ws_size >= (161ull << 20));

    if (fullPath) {
        float*  Mmat = (float*)(ws);
        float*  Minv = (float*)(ws + (16ull << 20));
        float*  Ebuf = (float*)(ws + (32ull << 20));
        unsigned short* Mh  = (unsigned short*)(ws + (48ull << 20));
        unsigned short* Ml  = (unsigned short*)(ws + (56ull << 20));
        unsigned short* Ahh = (unsigned short*)(ws + (64ull << 20));
        unsigned short* All = (unsigned short*)(ws + (80ull << 20));
        unsigned short* Fhh = (unsigned short*)(ws + (96ull << 20));   // = AT_h early
        unsigned short* Fll = (unsigned short*)(ws + (112ull << 20));  // = AT_l early
        unsigned int*   G   = (unsigned int*)(ws + (128ull << 20));
        char* tail = ws + (160ull << 20);
        float* c0  = (float*)(tail);
        float* d0  = (float*)(tail + 65536);
        float* ua  = (float*)(tail + 196608);
        float* Gdr = (float*)(tail + 327680);

        // 1) A^T split-bf16 (F slots) + A split-bf16, one pass
        prep_a<<<dim3(8, 4, 64), 256, 0, stream>>>(A, Fhh, Fll, Ahh, All);

        // 2) Mmat = RHO*(A^T)(A^T)^T + diag(P)+sigma   [MFMA, LDS-staged Y]
        mfma_nt<<<dim3(4, 4, 64), 256, 0, stream>>>(
            Fhh, Fll, Fhh, Fll, 512, 131072, 131072,
            (void*)Mmat, nullptr, 256, 65536, 0, 0, P, RHO_);

        // 3) Full Schur inversion chain (+ split-bf16 Minv), one kernel
        schur_inv<<<64, 256, 0, stream>>>(Mmat, Ebuf, Minv, Mh, Ml);

        // 4) c0 = -Minv q ; d0 = A c0
        c0d0_kernel<<<64, 512, 0, stream>>>(Minv, q, A, c0, d0);

        // 5) F = A * Minv^T -> split-bf16 (overwrites AT slots)
        mfma_nt<<<dim3(4, 8, 64), 256, 0, stream>>>(
            Ahh, All, Mh, Ml, 256, 131072, 65536,
            (void*)Fhh, (void*)Fll, 256, 131072, 0, 1, nullptr, 1.f);

        // 6) G = F * A^T -> f16 pair-packed + diag residual
        mfma_nt<<<dim3(8, 8, 64), 256, 0, stream>>>(
            Fhh, Fll, Ahh, All, 256, 131072, 131072,
            (void*)G, (void*)Gdr, 512, 131072, 512, 2, nullptr, 1.f);

        // 7) 200 ADMM iterations (R7-proven solver config)
        solver_reg<<<64, 512, 0, stream>>>(G, Gdr, d0, l, u, ua);

        // 8) x = c0 + Minv A^T u
        finalx_split<<<64, 256, 0, stream>>>(Mh, Ml, c0, ua, A, out);
    } else {
        // ---------------- fallback: R3-style sequence (fits ~64.5 MB) -------
        float*  Mmat = (float*)(ws);
        __half* Fh   = (__half*)(ws);
        float*  Minv = (float*)(ws + (16ull << 20));
        float*  E    = (float*)(ws + (32ull << 20));
        float*  T    = (float*)(ws + (36ull << 20));
        float*  S    = (float*)(ws + (40ull << 20));
        float*  V    = (float*)(ws + (44ull << 20));
        __half* G    = (__half*)(ws + (32ull << 20));
        char*   tail = ws + (64ull << 20);
        float*  c0   = (float*)(tail);
        float*  d0   = (float*)(tail + 65536);
        float*  ua   = (float*)(tail + 196608);
        float*  Gdr  = (float*)(tail + 327680);

        gemm_bt<<<dim3(4, 4, 64), 256, 0, stream>>>(
            A, nullptr, 256, 131072, 1,  A, 256, 131072, 0,
            nullptr, 0, 0,  Mmat, nullptr, 256, 65536,
            RHO_, 0.f, 256, 256, 512, 0, nullptr, 0);
        add_diag<<<64, 256, 0, stream>>>(Mmat, P);
        gj128_blk<<<64, 256, 65536, stream>>>(Mmat, 256, 65536, E, 128, 16384);
        gemm_bt<<<dim3(2, 2, 64), 256, 0, stream>>>(
            Mmat + 128 * 256, nullptr, 256, 65536, 0,  E, 128, 16384, 0,
            nullptr, 0, 0,  T, nullptr, 128, 16384,
            1.f, 0.f, 128, 128, 128, 0, nullptr, 0);
        gemm_bt<<<dim3(2, 2, 64), 256, 0, stream>>>(
            T, nullptr, 128, 16384, 0,  Mmat + 128, 256, 65536, 0,
            Mmat + 128 * 256 + 128, 256, 65536,
            S, nullptr, 128, 16384,
            -1.f, 1.f, 128, 128, 128, 0, nullptr, 0);
        gj128_blk<<<64, 256, 65536, stream>>>(S, 128, 16384, Minv + 128 * 256 + 128, 256, 65536);
        gemm_bt<<<dim3(2, 2, 64), 256, 0, stream>>>(
            Minv + 128 * 256 + 128, nullptr, 256, 65536, 0,  T, 128, 16384, 0,
            nullptr, 0, 0,  V, nullptr, 128, 16384,
            1.f, 0.f, 128, 128, 128, 0, nullptr, 0);
        gemm_bt<<<dim3(2, 2, 64), 256, 0, stream>>>(
            T, nullptr, 128, 16384, 1,  V, 128, 16384, 0,
            E, 128, 16384,
            Minv, nullptr, 256, 65536,
            1.f, 1.f, 128, 128, 128, 0, nullptr, 0);
        assemble_offdiag<<<64, 256, 0, stream>>>(Minv, V);
        c0d0_kernel<<<64, 512, 0, stream>>>(Minv, q, A, c0, d0);
        gemm_bt<<<dim3(4, 8, 64), 256, 0, stream>>>(
            A, nullptr, 256, 131072, 0,  Minv, 256, 65536, 0,
            nullptr, 0, 0,  nullptr, Fh, 256, 131072,
            1.f, 0.f, 512, 256, 256, 0, nullptr, 0);
        gemm_bt<<<dim3(8, 8, 64), 256, 0, stream>>>(
            nullptr, Fh, 256, 131072, 0,  A, 256, 131072, 1,
            nullptr, 0, 0,  nullptr, G, 512, 262144,
            1.f, 0.f, 512, 512, 256, 1, Gdr, 512);
        solver_reg<<<64, 512, 0, stream>>>((const unsigned int*)G, Gdr, d0, l, u, ua);
        finalx<<<64, 256, 0, stream>>>(Minv, c0, ua, A, out);
    }
}